// Round 3
// baseline (562.311 us; speedup 1.0000x reference)
//
#include <hip/hip_runtime.h>
#include <hip/hip_bf16.h>
#include <cmath>

typedef __hip_bfloat16 bf16;
typedef __attribute__((ext_vector_type(8))) short bf16x8;
typedef __attribute__((ext_vector_type(4))) float f32x4;

static __device__ __forceinline__ float b2f(bf16 v) { return __bfloat162float(v); }
static __device__ __forceinline__ bf16 f2b(float v) { return __float2bfloat16(v); }

// async global->LDS, 16B per lane; LDS dst is wave-uniform base + lane*16 (implicit)
static __device__ __forceinline__ void gl2lds16(const bf16* g, bf16* l) {
  __builtin_amdgcn_global_load_lds(
      (const __attribute__((address_space(1))) void*)g,
      (__attribute__((address_space(3))) void*)l, 16, 0, 0);
}

static __device__ __forceinline__ float gelu_exact(float v) {
  return 0.5f * v * (1.0f + erff(v * 0.70710678118f));
}

// ---------------- f32 -> bf16 convert, 4 elems/thread ----------------
__global__ __launch_bounds__(256) void cvt_k(const float* __restrict__ in,
                                             bf16* __restrict__ out, int n)
{
  int idx = (blockIdx.x * 256 + threadIdx.x) * 4;
  if (idx >= n) return;
  float4 v = *(const float4*)(in + idx);
  union { bf16 b[4]; ushort4 u; } o;
  o.b[0] = f2b(v.x); o.b[1] = f2b(v.y); o.b[2] = f2b(v.z); o.b[3] = f2b(v.w);
  *(ushort4*)(out + idx) = o.u;
}

// ---------------- LayerNorm over rows of 1024: f32 in, bf16 out ----------------
__global__ __launch_bounds__(256) void ln_k(const float* __restrict__ X, bf16* __restrict__ Y,
                                            const float* __restrict__ gamma,
                                            const float* __restrict__ beta)
{
  __shared__ float red[16];
  const int row = blockIdx.x, tid = threadIdx.x;
  const float* xr = X + (size_t)row * 1024;
  float v[4], s = 0.f, s2 = 0.f;
#pragma unroll
  for (int i = 0; i < 4; ++i) {
    float xv = xr[tid + i * 256];
    v[i] = xv; s += xv; s2 += xv * xv;
  }
#pragma unroll
  for (int m = 32; m; m >>= 1) { s += __shfl_xor(s, m, 64); s2 += __shfl_xor(s2, m, 64); }
  const int wid = tid >> 6;
  if ((tid & 63) == 0) { red[wid] = s; red[wid + 8] = s2; }
  __syncthreads();
  s  = red[0] + red[1] + red[2] + red[3];
  s2 = red[8] + red[9] + red[10] + red[11];
  const float mu  = s * (1.f / 1024.f);
  const float var = s2 * (1.f / 1024.f) - mu * mu;
  const float rs  = rsqrtf(var + 1e-5f);
#pragma unroll
  for (int i = 0; i < 4; ++i) {
    int c = tid + i * 256;
    Y[(size_t)row * 1024 + c] = f2b((v[i] - mu) * rs * gamma[c] + beta[c]);
  }
}

// ---------------- GEMM: C = A[M,K](bf16) * W[N,K](bf16)^T + bias(f32), fused epilogues ----------------
// EPI 0: out bf16 = gelu(v)
// EPI 1: out f32  = v * exp(-m * exp(a))            (aux0 = a f32)
// EPI 2: out f32  = v * aux0[m,n] + aux1[m,n]       (aux0 = cwhz f32, aux1 = z f32)
// EPI 3: out f32  = v + aux0[m,n]                   (aux0 = x1 f32)
template<int EPI>
__global__ __launch_bounds__(256) void gemm_k(
    const bf16* __restrict__ A, const bf16* __restrict__ W,
    const float* __restrict__ bias, void* __restrict__ Out,
    const void* __restrict__ aux0, const void* __restrict__ aux1,
    int M, int N, int K)
{
  __shared__ bf16 As[128 * 32];
  __shared__ bf16 Bs[128 * 32];
  const int tid = threadIdx.x;
  const int wid = tid >> 6, lane = tid & 63;
  const int quad = lane >> 4, l16 = lane & 15;
  const int wm = wid >> 1, wn = wid & 1;
  const int m0 = blockIdx.y * 128, n0 = blockIdx.x * 128;

  f32x4 acc[4][4];
#pragma unroll
  for (int i = 0; i < 4; ++i)
#pragma unroll
    for (int j = 0; j < 4; ++j) acc[i][j] = (f32x4){0.f, 0.f, 0.f, 0.f};

  for (int k0 = 0; k0 < K; k0 += 32) {
    __syncthreads();
#pragma unroll
    for (int r = 0; r < 2; ++r) {
      int c = r * 256 + wid * 64 + lane;       // 16B chunk id within the 128x32 tile
      int row = c >> 2, kk = (c & 3) << 3;
      gl2lds16(A + (size_t)(m0 + row) * K + k0 + kk, As + (size_t)(r * 256 + wid * 64) * 8);
      gl2lds16(W + (size_t)(n0 + row) * K + k0 + kk, Bs + (size_t)(r * 256 + wid * 64) * 8);
    }
    __syncthreads();
    bf16x8 af[4], bfr[4];
#pragma unroll
    for (int i = 0; i < 4; ++i)
      af[i] = *(const bf16x8*)(As + (wm * 64 + i * 16 + l16) * 32 + quad * 8);
#pragma unroll
    for (int j = 0; j < 4; ++j)
      bfr[j] = *(const bf16x8*)(Bs + (wn * 64 + j * 16 + l16) * 32 + quad * 8);
#pragma unroll
    for (int i = 0; i < 4; ++i)
#pragma unroll
      for (int j = 0; j < 4; ++j)
        acc[i][j] = __builtin_amdgcn_mfma_f32_16x16x32_bf16(af[i], bfr[j], acc[i][j], 0, 0, 0);
  }

  float expa = 0.f;
  if (EPI == 1) expa = expf(((const float*)aux0)[0]);

#pragma unroll
  for (int i = 0; i < 4; ++i) {
    const int gm_base = m0 + wm * 64 + i * 16 + quad * 4;
#pragma unroll
    for (int j = 0; j < 4; ++j) {
      const int gn = n0 + wn * 64 + j * 16 + l16;
      const float bv = bias[gn];
#pragma unroll
      for (int r = 0; r < 4; ++r) {
        const int gm = gm_base + r;
        const size_t off = (size_t)gm * N + gn;
        float v = acc[i][j][r] + bv;
        if (EPI == 0) {
          ((bf16*)Out)[off] = f2b(gelu_exact(v));
        } else if (EPI == 1) {
          ((float*)Out)[off] = v * expf(-(float)gm * expa);
        } else if (EPI == 2) {
          ((float*)Out)[off] = v * ((const float*)aux0)[off] + ((const float*)aux1)[off];
        } else { // EPI == 3
          ((float*)Out)[off] = v + ((const float*)aux0)[off];
        }
      }
    }
  }
}

// ---------------- causal depthwise conv: out[b,t,d] = sum_{s<=t} wh[s,d]*zn[b,t-s,d] ----------------
__global__ __launch_bounds__(256) void conv_k(
    const bf16* __restrict__ zn,    // [B, L, D] bf16
    const float* __restrict__ wh,   // [L, D] f32 (window already applied)
    const float* __restrict__ a,
    float* __restrict__ out)        // [B, L, D] f32
{
  __shared__ float whs[64 * 64];
  __shared__ float znt[127 * 64];
  const int tid = threadIdx.x;
  const int dd = tid & 63, ttg = tid >> 6;
  const int t0 = blockIdx.x * 64, d0 = blockIdx.y * 64, b = blockIdx.z;
  const float expa = expf(a[0]);
  const float smax = 20.7f / expa;   // exp(-smax*expa) ~ 1e-9: tail negligible

  float acc[16];
#pragma unroll
  for (int q = 0; q < 16; ++q) acc[q] = 0.f;

  for (int sb = 0; sb <= t0 + 63; sb += 64) {
    if ((float)sb > smax) break;
    for (int idx = tid; idx < 64 * 64; idx += 256) {
      int ss = idx >> 6, d2 = idx & 63;
      int s = sb + ss;
      whs[idx] = (s < 2048) ? wh[(size_t)s * 1024 + d0 + d2] : 0.f;
    }
    for (int idx = tid; idx < 127 * 64; idx += 256) {
      int uu = idx >> 6, d2 = idx & 63;
      int u = t0 - sb - 63 + uu;
      znt[idx] = (u >= 0) ? b2f(zn[((size_t)b * 2048 + u) * 1024 + d0 + d2]) : 0.f;
    }
    __syncthreads();
#pragma unroll 4
    for (int ss = 0; ss < 64; ++ss) {
      float wv = whs[ss * 64 + dd];
#pragma unroll
      for (int q = 0; q < 16; ++q) {
        int tt = ttg * 16 + q;
        acc[q] += wv * znt[(tt - ss + 63) * 64 + dd];
      }
    }
    __syncthreads();
  }
#pragma unroll
  for (int q = 0; q < 16; ++q) {
    int t = t0 + ttg * 16 + q;
    out[((size_t)b * 2048 + t) * 1024 + d0 + dd] = acc[q];
  }
}

extern "C" void kernel_launch(void* const* d_in, const int* in_sizes, int n_in,
                              void* d_out, int out_size, void* d_ws, size_t ws_size,
                              hipStream_t stream)
{
  const float* z      = (const float*)d_in[0];
  const float* x      = (const float*)d_in[1];
  const float* a      = (const float*)d_in[2];
  const float* pe     = (const float*)d_in[3];
  const float* w_pos1 = (const float*)d_in[4];
  const float* b_pos1 = (const float*)d_in[5];
  const float* w_pos2 = (const float*)d_in[6];
  const float* b_pos2 = (const float*)d_in[7];
  const float* w1     = (const float*)d_in[8];
  const float* b1     = (const float*)d_in[9];
  const float* w2     = (const float*)d_in[10];
  const float* b2     = (const float*)d_in[11];
  const float* w3     = (const float*)d_in[12];
  const float* b3     = (const float*)d_in[13];
  const float* w4     = (const float*)d_in[14];
  const float* b4     = (const float*)d_in[15];
  const float* ln_g   = (const float*)d_in[16];
  const float* ln_b   = (const float*)d_in[17];

  char* ws = (char*)d_ws;
  // bf16 weight/activation arena (offsets in bytes, all 16B-aligned)
  bf16* pe_bf  = (bf16*)(ws + 0);           //  2048*128
  bf16* wp1_bf = (bf16*)(ws + 524288);      //  1152*128
  bf16* wp2_bf = (bf16*)(ws + 819200);      //  1024*1152
  bf16* w1_bf  = (bf16*)(ws + 3178496);     //  2048*1024
  bf16* w2_bf  = (bf16*)(ws + 7372800);     //  1024*2048
  bf16* w3_bf  = (bf16*)(ws + 11567104);    //  2048*1024
  bf16* w4_bf  = (bf16*)(ws + 15761408);    //  1024*2048
  bf16* h1     = (bf16*)(ws + 19955712);    //  2048*1152
  bf16* zn_bf  = (bf16*)(ws + 24674304);    //  8192*1024 bf16 (dead after conv)
  bf16* x_bf   = (bf16*)(ws + 41451520);    //  8192*1024 bf16 (dead after gemm5)
  float* wh    = (float*)(ws + 58228736);   //  2048*1024 f32
  float* cwhz  = (float*)(ws + 66617344);   //  8192*1024 f32 (dead after gemm6)
  bf16*  x1n   = (bf16*)(ws + 66617344);    //  reuses cwhz region after gemm6
  bf16*  g     = (bf16*)(ws + 100171776);   //  8192*2048 bf16 (g1 then g3)
  float* x1    = (float*)(ws + 24674304);   //  8192*1024 f32, reuses zn_bf+x_bf region
  float* out   = (float*)d_out;
  // total ws footprint: 133,726,208 B (~127.5 MB)

  // 0. convert weights + activations to bf16
  cvt_k<<<  256, 256, 0, stream>>>(pe,     pe_bf,  262144);
  cvt_k<<<  144, 256, 0, stream>>>(w_pos1, wp1_bf, 147456);
  cvt_k<<< 1152, 256, 0, stream>>>(w_pos2, wp2_bf, 1179648);
  cvt_k<<< 2048, 256, 0, stream>>>(w1,     w1_bf,  2097152);
  cvt_k<<< 2048, 256, 0, stream>>>(w2,     w2_bf,  2097152);
  cvt_k<<< 2048, 256, 0, stream>>>(w3,     w3_bf,  2097152);
  cvt_k<<< 2048, 256, 0, stream>>>(w4,     w4_bf,  2097152);
  cvt_k<<< 8192, 256, 0, stream>>>(x,      x_bf,   8388608);

  // 1. zn = LN(z) -> bf16                          [8192 rows]
  ln_k<<<8192, 256, 0, stream>>>(z, zn_bf, ln_g, ln_b);
  // 2. h1 = gelu(pe @ w_pos1^T + b_pos1) -> bf16   [2048, 1152], K=128
  gemm_k<0><<<dim3(9, 16), 256, 0, stream>>>(pe_bf, wp1_bf, b_pos1, h1, nullptr, nullptr, 2048, 1152, 128);
  // 3. wh = window * (h1 @ w_pos2^T + b_pos2) f32  [2048, 1024], K=1152
  gemm_k<1><<<dim3(8, 16), 256, 0, stream>>>(h1, wp2_bf, b_pos2, wh, a, nullptr, 2048, 1024, 1152);
  // 4. cwhz = causal depthwise conv(zn, wh) f32    [4, 2048, 1024]
  conv_k<<<dim3(32, 16, 4), 256, 0, stream>>>(zn_bf, wh, a, cwhz);
  // 5. g1 = gelu(x @ w1^T + b1) -> bf16            [8192, 2048], K=1024
  gemm_k<0><<<dim3(16, 64), 256, 0, stream>>>(x_bf, w1_bf, b1, g, nullptr, nullptr, 8192, 2048, 1024);
  // 6. x1 = (g1 @ w2^T + b2) * cwhz + z   f32      [8192, 1024], K=2048
  gemm_k<2><<<dim3(8, 64), 256, 0, stream>>>(g, w2_bf, b2, x1, cwhz, z, 8192, 1024, 2048);
  // 7. x1n = LN(x1) -> bf16
  ln_k<<<8192, 256, 0, stream>>>(x1, x1n, ln_g, ln_b);
  // 8. g3 = gelu(x1n @ w3^T + b3) -> bf16          [8192, 2048], K=1024
  gemm_k<0><<<dim3(16, 64), 256, 0, stream>>>(x1n, w3_bf, b3, g, nullptr, nullptr, 8192, 2048, 1024);
  // 9. out = (g3 @ w4^T + b4) + x1  f32            [8192, 1024], K=2048
  gemm_k<3><<<dim3(8, 64), 256, 0, stream>>>(g, w4_bf, b4, out, x1, nullptr, 8192, 1024, 2048);
}

// Round 4
// 558.505 us; speedup vs baseline: 1.0068x; 1.0068x over previous
//
#include <hip/hip_runtime.h>
#include <hip/hip_bf16.h>
#include <cmath>

typedef __hip_bfloat16 bf16;
typedef __attribute__((ext_vector_type(8))) short bf16x8;
typedef __attribute__((ext_vector_type(4))) float f32x4;

static __device__ __forceinline__ float b2f(bf16 v) { return __bfloat162float(v); }
static __device__ __forceinline__ bf16 f2b(float v) { return __float2bfloat16(v); }

// async global->LDS, 16B per lane; LDS dst is wave-uniform base + lane*16 (implicit)
static __device__ __forceinline__ void gl2lds16(const bf16* g, bf16* l) {
  __builtin_amdgcn_global_load_lds(
      (const __attribute__((address_space(1))) void*)g,
      (__attribute__((address_space(3))) void*)l, 16, 0, 0);
}

static __device__ __forceinline__ float gelu_exact(float v) {
  return 0.5f * v * (1.0f + erff(v * 0.70710678118f));
}

// ---------------- f32 -> bf16 convert, 4 elems/thread ----------------
__global__ __launch_bounds__(256) void cvt_k(const float* __restrict__ in,
                                             bf16* __restrict__ out, int n)
{
  int idx = (blockIdx.x * 256 + threadIdx.x) * 4;
  if (idx >= n) return;
  float4 v = *(const float4*)(in + idx);
  union { bf16 b[4]; ushort4 u; } o;
  o.b[0] = f2b(v.x); o.b[1] = f2b(v.y); o.b[2] = f2b(v.z); o.b[3] = f2b(v.w);
  *(ushort4*)(out + idx) = o.u;
}

// ---------------- LayerNorm over rows of 1024: f32 in, bf16 out ----------------
__global__ __launch_bounds__(256) void ln_k(const float* __restrict__ X, bf16* __restrict__ Y,
                                            const float* __restrict__ gamma,
                                            const float* __restrict__ beta)
{
  __shared__ float red[16];
  const int row = blockIdx.x, tid = threadIdx.x;
  const float* xr = X + (size_t)row * 1024;
  float v[4], s = 0.f, s2 = 0.f;
#pragma unroll
  for (int i = 0; i < 4; ++i) {
    float xv = xr[tid + i * 256];
    v[i] = xv; s += xv; s2 += xv * xv;
  }
#pragma unroll
  for (int m = 32; m; m >>= 1) { s += __shfl_xor(s, m, 64); s2 += __shfl_xor(s2, m, 64); }
  const int wid = tid >> 6;
  if ((tid & 63) == 0) { red[wid] = s; red[wid + 8] = s2; }
  __syncthreads();
  s  = red[0] + red[1] + red[2] + red[3];
  s2 = red[8] + red[9] + red[10] + red[11];
  const float mu  = s * (1.f / 1024.f);
  const float var = s2 * (1.f / 1024.f) - mu * mu;
  const float rs  = rsqrtf(var + 1e-5f);
#pragma unroll
  for (int i = 0; i < 4; ++i) {
    int c = tid + i * 256;
    Y[(size_t)row * 1024 + c] = f2b((v[i] - mu) * rs * gamma[c] + beta[c]);
  }
}

// ---------------- GEMM: C = A[M,K](bf16) * W[N,K](bf16)^T + bias(f32), fused epilogues ----------------
// LDS layout (per 128x32 tile): 512 slots of 16B. Slot p holds global chunk
// (row = p>>2, kchunk = (p&3) ^ ((p>>3)&3))  -- XOR swizzle so that fragment
// reads (stride 64B in row) cover all 32 banks per 8 rows (2-way = free).
// EPI 0: out bf16 = gelu(v)
// EPI 1: out f32  = v * exp(-m * exp(a))            (aux0 = a f32)
// EPI 2: out f32  = v * aux0[m,n] + aux1[m,n]       (aux0 = cwhz f32, aux1 = z f32)
// EPI 3: out f32  = v + aux0[m,n]                   (aux0 = x1 f32)
template<int EPI>
__global__ __launch_bounds__(256) void gemm_k(
    const bf16* __restrict__ A, const bf16* __restrict__ W,
    const float* __restrict__ bias, void* __restrict__ Out,
    const void* __restrict__ aux0, const void* __restrict__ aux1,
    int M, int N, int K)
{
  __shared__ bf16 As[128 * 32];
  __shared__ bf16 Bs[128 * 32];
  const int tid = threadIdx.x;
  const int wid = tid >> 6, lane = tid & 63;
  const int quad = lane >> 4, l16 = lane & 15;
  const int wm = wid >> 1, wn = wid & 1;
  const int m0 = blockIdx.y * 128, n0 = blockIdx.x * 128;

  f32x4 acc[4][4];
#pragma unroll
  for (int i = 0; i < 4; ++i)
#pragma unroll
    for (int j = 0; j < 4; ++j) acc[i][j] = (f32x4){0.f, 0.f, 0.f, 0.f};

  // per-lane swizzled source chunk for staging (slot = r*256 + wid*64 + lane)
  int srow[2], skc[2];
#pragma unroll
  for (int r = 0; r < 2; ++r) {
    int p = r * 256 + wid * 64 + lane;
    srow[r] = p >> 2;
    skc[r]  = ((p & 3) ^ ((p >> 3) & 3)) << 3;   // element offset within row
  }
  // swizzled LDS slot for each fragment read
  int apos[4], bpos[4];
#pragma unroll
  for (int i = 0; i < 4; ++i) {
    int ar = wm * 64 + i * 16 + l16;
    apos[i] = (ar * 4 + (quad ^ ((ar >> 1) & 3))) * 8;
    int br = wn * 64 + i * 16 + l16;
    bpos[i] = (br * 4 + (quad ^ ((br >> 1) & 3))) * 8;
  }

  for (int k0 = 0; k0 < K; k0 += 32) {
    __syncthreads();
#pragma unroll
    for (int r = 0; r < 2; ++r) {
      gl2lds16(A + (size_t)(m0 + srow[r]) * K + k0 + skc[r], As + (size_t)(r * 256 + wid * 64) * 8);
      gl2lds16(W + (size_t)(n0 + srow[r]) * K + k0 + skc[r], Bs + (size_t)(r * 256 + wid * 64) * 8);
    }
    __syncthreads();
    bf16x8 af[4], bfr[4];
#pragma unroll
    for (int i = 0; i < 4; ++i) af[i]  = *(const bf16x8*)(As + apos[i]);
#pragma unroll
    for (int j = 0; j < 4; ++j) bfr[j] = *(const bf16x8*)(Bs + bpos[j]);
#pragma unroll
    for (int i = 0; i < 4; ++i)
#pragma unroll
      for (int j = 0; j < 4; ++j)
        acc[i][j] = __builtin_amdgcn_mfma_f32_16x16x32_bf16(af[i], bfr[j], acc[i][j], 0, 0, 0);
  }

  float expa = 0.f;
  if (EPI == 1) expa = expf(((const float*)aux0)[0]);

#pragma unroll
  for (int i = 0; i < 4; ++i) {
    const int gm_base = m0 + wm * 64 + i * 16 + quad * 4;
#pragma unroll
    for (int j = 0; j < 4; ++j) {
      const int gn = n0 + wn * 64 + j * 16 + l16;
      const float bv = bias[gn];
#pragma unroll
      for (int r = 0; r < 4; ++r) {
        const int gm = gm_base + r;
        const size_t off = (size_t)gm * N + gn;
        float v = acc[i][j][r] + bv;
        if (EPI == 0) {
          ((bf16*)Out)[off] = f2b(gelu_exact(v));
        } else if (EPI == 1) {
          ((float*)Out)[off] = v * expf(-(float)gm * expa);
        } else if (EPI == 2) {
          ((float*)Out)[off] = v * ((const float*)aux0)[off] + ((const float*)aux1)[off];
        } else { // EPI == 3
          ((float*)Out)[off] = v + ((const float*)aux0)[off];
        }
      }
    }
  }
}

// ---------------- causal depthwise conv: out[b,t,d] = sum_{s<=t} wh[s,d]*zn[b,t-s,d] ----------------
__global__ __launch_bounds__(256) void conv_k(
    const bf16* __restrict__ zn,    // [B, L, D] bf16
    const float* __restrict__ wh,   // [L, D] f32 (window already applied)
    const float* __restrict__ a,
    float* __restrict__ out)        // [B, L, D] f32
{
  __shared__ float whs[64 * 64];
  __shared__ float znt[127 * 64];
  const int tid = threadIdx.x;
  const int dd = tid & 63, ttg = tid >> 6;
  const int t0 = blockIdx.x * 64, d0 = blockIdx.y * 64, b = blockIdx.z;
  const float expa = expf(a[0]);
  const float smax = 20.7f / expa;   // exp(-smax*expa) ~ 1e-9: tail negligible

  float acc[16];
#pragma unroll
  for (int q = 0; q < 16; ++q) acc[q] = 0.f;

  for (int sb = 0; sb <= t0 + 63; sb += 64) {
    if ((float)sb > smax) break;
    for (int idx = tid; idx < 64 * 64; idx += 256) {
      int ss = idx >> 6, d2 = idx & 63;
      int s = sb + ss;
      whs[idx] = (s < 2048) ? wh[(size_t)s * 1024 + d0 + d2] : 0.f;
    }
    for (int idx = tid; idx < 127 * 64; idx += 256) {
      int uu = idx >> 6, d2 = idx & 63;
      int u = t0 - sb - 63 + uu;
      znt[idx] = (u >= 0) ? b2f(zn[((size_t)b * 2048 + u) * 1024 + d0 + d2]) : 0.f;
    }
    __syncthreads();
#pragma unroll 4
    for (int ss = 0; ss < 64; ++ss) {
      float wv = whs[ss * 64 + dd];
#pragma unroll
      for (int q = 0; q < 16; ++q) {
        int tt = ttg * 16 + q;
        acc[q] += wv * znt[(tt - ss + 63) * 64 + dd];
      }
    }
    __syncthreads();
  }
#pragma unroll
  for (int q = 0; q < 16; ++q) {
    int t = t0 + ttg * 16 + q;
    out[((size_t)b * 2048 + t) * 1024 + d0 + dd] = acc[q];
  }
}

extern "C" void kernel_launch(void* const* d_in, const int* in_sizes, int n_in,
                              void* d_out, int out_size, void* d_ws, size_t ws_size,
                              hipStream_t stream)
{
  const float* z      = (const float*)d_in[0];
  const float* x      = (const float*)d_in[1];
  const float* a      = (const float*)d_in[2];
  const float* pe     = (const float*)d_in[3];
  const float* w_pos1 = (const float*)d_in[4];
  const float* b_pos1 = (const float*)d_in[5];
  const float* w_pos2 = (const float*)d_in[6];
  const float* b_pos2 = (const float*)d_in[7];
  const float* w1     = (const float*)d_in[8];
  const float* b1     = (const float*)d_in[9];
  const float* w2     = (const float*)d_in[10];
  const float* b2     = (const float*)d_in[11];
  const float* w3     = (const float*)d_in[12];
  const float* b3     = (const float*)d_in[13];
  const float* w4     = (const float*)d_in[14];
  const float* b4     = (const float*)d_in[15];
  const float* ln_g   = (const float*)d_in[16];
  const float* ln_b   = (const float*)d_in[17];

  char* ws = (char*)d_ws;
  bf16* pe_bf  = (bf16*)(ws + 0);           //  2048*128
  bf16* wp1_bf = (bf16*)(ws + 524288);      //  1152*128
  bf16* wp2_bf = (bf16*)(ws + 819200);      //  1024*1152
  bf16* w1_bf  = (bf16*)(ws + 3178496);     //  2048*1024
  bf16* w2_bf  = (bf16*)(ws + 7372800);     //  1024*2048
  bf16* w3_bf  = (bf16*)(ws + 11567104);    //  2048*1024
  bf16* w4_bf  = (bf16*)(ws + 15761408);    //  1024*2048
  bf16* h1     = (bf16*)(ws + 19955712);    //  2048*1152
  bf16* zn_bf  = (bf16*)(ws + 24674304);    //  8192*1024 bf16 (dead after conv)
  bf16* x_bf   = (bf16*)(ws + 41451520);    //  8192*1024 bf16 (dead after gemm5)
  float* wh    = (float*)(ws + 58228736);   //  2048*1024 f32
  float* cwhz  = (float*)(ws + 66617344);   //  8192*1024 f32 (dead after gemm6)
  bf16*  x1n   = (bf16*)(ws + 66617344);    //  reuses cwhz region after gemm6
  bf16*  g     = (bf16*)(ws + 100171776);   //  8192*2048 bf16 (g1 then g3)
  float* x1    = (float*)(ws + 24674304);   //  8192*1024 f32, reuses zn_bf+x_bf region
  float* out   = (float*)d_out;

  // 0. convert weights + activations to bf16
  cvt_k<<<  256, 256, 0, stream>>>(pe,     pe_bf,  262144);
  cvt_k<<<  144, 256, 0, stream>>>(w_pos1, wp1_bf, 147456);
  cvt_k<<< 1152, 256, 0, stream>>>(w_pos2, wp2_bf, 1179648);
  cvt_k<<< 2048, 256, 0, stream>>>(w1,     w1_bf,  2097152);
  cvt_k<<< 2048, 256, 0, stream>>>(w2,     w2_bf,  2097152);
  cvt_k<<< 2048, 256, 0, stream>>>(w3,     w3_bf,  2097152);
  cvt_k<<< 2048, 256, 0, stream>>>(w4,     w4_bf,  2097152);
  cvt_k<<< 8192, 256, 0, stream>>>(x,      x_bf,   8388608);

  // 1. zn = LN(z) -> bf16
  ln_k<<<8192, 256, 0, stream>>>(z, zn_bf, ln_g, ln_b);
  // 2. h1 = gelu(pe @ w_pos1^T + b_pos1) -> bf16   [2048, 1152], K=128
  gemm_k<0><<<dim3(9, 16), 256, 0, stream>>>(pe_bf, wp1_bf, b_pos1, h1, nullptr, nullptr, 2048, 1152, 128);
  // 3. wh = window * (h1 @ w_pos2^T + b_pos2) f32  [2048, 1024], K=1152
  gemm_k<1><<<dim3(8, 16), 256, 0, stream>>>(h1, wp2_bf, b_pos2, wh, a, nullptr, 2048, 1024, 1152);
  // 4. cwhz = causal depthwise conv(zn, wh) f32    [4, 2048, 1024]
  conv_k<<<dim3(32, 16, 4), 256, 0, stream>>>(zn_bf, wh, a, cwhz);
  // 5. g1 = gelu(x @ w1^T + b1) -> bf16            [8192, 2048], K=1024
  gemm_k<0><<<dim3(16, 64), 256, 0, stream>>>(x_bf, w1_bf, b1, g, nullptr, nullptr, 8192, 2048, 1024);
  // 6. x1 = (g1 @ w2^T + b2) * cwhz + z   f32      [8192, 1024], K=2048
  gemm_k<2><<<dim3(8, 64), 256, 0, stream>>>(g, w2_bf, b2, x1, cwhz, z, 8192, 1024, 2048);
  // 7. x1n = LN(x1) -> bf16
  ln_k<<<8192, 256, 0, stream>>>(x1, x1n, ln_g, ln_b);
  // 8. g3 = gelu(x1n @ w3^T + b3) -> bf16          [8192, 2048], K=1024
  gemm_k<0><<<dim3(16, 64), 256, 0, stream>>>(x1n, w3_bf, b3, g, nullptr, nullptr, 8192, 2048, 1024);
  // 9. out = (g3 @ w4^T + b4) + x1  f32            [8192, 1024], K=2048
  gemm_k<3><<<dim3(8, 64), 256, 0, stream>>>(g, w4_bf, b4, out, x1, nullptr, 8192, 1024, 2048);
}

// Round 5
// 513.168 us; speedup vs baseline: 1.0958x; 1.0883x over previous
//
#include <hip/hip_runtime.h>
#include <hip/hip_bf16.h>
#include <cmath>

typedef __hip_bfloat16 bf16;
typedef __attribute__((ext_vector_type(8))) short bf16x8;
typedef __attribute__((ext_vector_type(4))) float f32x4;

static __device__ __forceinline__ float b2f(bf16 v) { return __bfloat162float(v); }
static __device__ __forceinline__ bf16 f2b(float v) { return __float2bfloat16(v); }

// async global->LDS, 16B per lane; LDS dst is wave-uniform base + lane*16 (implicit)
static __device__ __forceinline__ void gl2lds16(const bf16* g, bf16* l) {
  __builtin_amdgcn_global_load_lds(
      (const __attribute__((address_space(1))) void*)g,
      (__attribute__((address_space(3))) void*)l, 16, 0, 0);
}

static __device__ __forceinline__ float gelu_exact(float v) {
  return 0.5f * v * (1.0f + erff(v * 0.70710678118f));
}

// ---------------- f32 -> bf16 convert, 4 elems/thread ----------------
__global__ __launch_bounds__(256) void cvt_k(const float* __restrict__ in,
                                             bf16* __restrict__ out, int n)
{
  int idx = (blockIdx.x * 256 + threadIdx.x) * 4;
  if (idx >= n) return;
  float4 v = *(const float4*)(in + idx);
  union { bf16 b[4]; ushort4 u; } o;
  o.b[0] = f2b(v.x); o.b[1] = f2b(v.y); o.b[2] = f2b(v.z); o.b[3] = f2b(v.w);
  *(ushort4*)(out + idx) = o.u;
}

// ---------------- LayerNorm over rows of 1024: f32 in, bf16 out ----------------
__global__ __launch_bounds__(256) void ln_k(const float* __restrict__ X, bf16* __restrict__ Y,
                                            const float* __restrict__ gamma,
                                            const float* __restrict__ beta)
{
  __shared__ float red[16];
  const int row = blockIdx.x, tid = threadIdx.x;
  const float* xr = X + (size_t)row * 1024;
  float v[4], s = 0.f, s2 = 0.f;
#pragma unroll
  for (int i = 0; i < 4; ++i) {
    float xv = xr[tid + i * 256];
    v[i] = xv; s += xv; s2 += xv * xv;
  }
#pragma unroll
  for (int m = 32; m; m >>= 1) { s += __shfl_xor(s, m, 64); s2 += __shfl_xor(s2, m, 64); }
  const int wid = tid >> 6;
  if ((tid & 63) == 0) { red[wid] = s; red[wid + 8] = s2; }
  __syncthreads();
  s  = red[0] + red[1] + red[2] + red[3];
  s2 = red[8] + red[9] + red[10] + red[11];
  const float mu  = s * (1.f / 1024.f);
  const float var = s2 * (1.f / 1024.f) - mu * mu;
  const float rs  = rsqrtf(var + 1e-5f);
#pragma unroll
  for (int i = 0; i < 4; ++i) {
    int c = tid + i * 256;
    Y[(size_t)row * 1024 + c] = f2b((v[i] - mu) * rs * gamma[c] + beta[c]);
  }
}

// ---------------- GEMM: C = A[M,K](bf16) * W[N,K](bf16)^T + bias(f32), fused epilogues ----------------
// BK=64. LDS tile = 128 rows x 8 chunks of 16B. Chunk c of row r stored at
// slot r*8 + (c ^ (r&7)) -> fragment reads (16 lanes, stride 128B) are 2-way
// bank-aliased (free); staging stays coalesced (permutation within 128B).
// EPI 0: out bf16 = gelu(v)
// EPI 1: out f32  = v * exp(-m * exp(a))            (aux0 = a f32)
// EPI 2: out f32  = v * aux0[m,n] + aux1[m,n]       (aux0 = cwhz f32, aux1 = z f32)
// EPI 3: out f32  = v + aux0[m,n]                   (aux0 = x1 f32)
template<int EPI>
__global__ __launch_bounds__(256) void gemm_k(
    const bf16* __restrict__ A, const bf16* __restrict__ W,
    const float* __restrict__ bias, void* __restrict__ Out,
    const void* __restrict__ aux0, const void* __restrict__ aux1,
    int M, int N, int K)
{
  __shared__ bf16 As[128 * 64];
  __shared__ bf16 Bs[128 * 64];
  const int tid = threadIdx.x;
  const int wid = tid >> 6, lane = tid & 63;
  const int quad = lane >> 4, l16 = lane & 15;
  const int wm = wid >> 1, wn = wid & 1;
  const int m0 = blockIdx.y * 128, n0 = blockIdx.x * 128;

  f32x4 acc[4][4];
#pragma unroll
  for (int i = 0; i < 4; ++i)
#pragma unroll
    for (int j = 0; j < 4; ++j) acc[i][j] = (f32x4){0.f, 0.f, 0.f, 0.f};

  // staging: 1024 chunks (128 rows x 8). chunk p -> row=p>>3, stored chunk cc=p&7,
  // fetched global k-chunk gc = cc ^ (row&7).
  int srow[4], sko[4];
#pragma unroll
  for (int r = 0; r < 4; ++r) {
    int p = r * 256 + wid * 64 + lane;
    srow[r] = p >> 3;
    sko[r]  = ((p & 7) ^ ((p >> 3) & 7)) << 3;   // element offset within row
  }
  // fragment LDS offsets (elements): row ar, chunk c = quad + 4*half
  int apos[4][2], bpos[4][2];
#pragma unroll
  for (int i = 0; i < 4; ++i) {
#pragma unroll
    for (int h = 0; h < 2; ++h) {
      int ar = wm * 64 + i * 16 + l16;
      apos[i][h] = (ar * 8 + ((quad + 4 * h) ^ (ar & 7))) * 8;
      int br = wn * 64 + i * 16 + l16;
      bpos[i][h] = (br * 8 + ((quad + 4 * h) ^ (br & 7))) * 8;
    }
  }

  for (int k0 = 0; k0 < K; k0 += 64) {
    __syncthreads();
#pragma unroll
    for (int r = 0; r < 4; ++r) {
      gl2lds16(A + (size_t)(m0 + srow[r]) * K + k0 + sko[r], As + (size_t)(r * 256 + wid * 64) * 8);
      gl2lds16(W + (size_t)(n0 + srow[r]) * K + k0 + sko[r], Bs + (size_t)(r * 256 + wid * 64) * 8);
    }
    __syncthreads();
    bf16x8 af[2][4], bfr[2][4];
#pragma unroll
    for (int h = 0; h < 2; ++h) {
#pragma unroll
      for (int i = 0; i < 4; ++i) af[h][i]  = *(const bf16x8*)(As + apos[i][h]);
#pragma unroll
      for (int j = 0; j < 4; ++j) bfr[h][j] = *(const bf16x8*)(Bs + bpos[j][h]);
    }
#pragma unroll
    for (int h = 0; h < 2; ++h)
#pragma unroll
      for (int i = 0; i < 4; ++i)
#pragma unroll
        for (int j = 0; j < 4; ++j)
          acc[i][j] = __builtin_amdgcn_mfma_f32_16x16x32_bf16(af[h][i], bfr[h][j], acc[i][j], 0, 0, 0);
  }

  float expa = 0.f;
  if (EPI == 1) expa = expf(((const float*)aux0)[0]);

#pragma unroll
  for (int i = 0; i < 4; ++i) {
    const int gm_base = m0 + wm * 64 + i * 16 + quad * 4;
#pragma unroll
    for (int j = 0; j < 4; ++j) {
      const int gn = n0 + wn * 64 + j * 16 + l16;
      const float bv = bias[gn];
#pragma unroll
      for (int r = 0; r < 4; ++r) {
        const int gm = gm_base + r;
        const size_t off = (size_t)gm * N + gn;
        float v = acc[i][j][r] + bv;
        if (EPI == 0) {
          ((bf16*)Out)[off] = f2b(gelu_exact(v));
        } else if (EPI == 1) {
          ((float*)Out)[off] = v * expf(-(float)gm * expa);
        } else if (EPI == 2) {
          ((float*)Out)[off] = v * ((const float*)aux0)[off] + ((const float*)aux1)[off];
        } else { // EPI == 3
          ((float*)Out)[off] = v + ((const float*)aux0)[off];
        }
      }
    }
  }
}

// ---------------- causal depthwise conv: out[b,t,d] = sum_{s<=t} wh[s,d]*zn[b,t-s,d] ----------------
__global__ __launch_bounds__(256) void conv_k(
    const bf16* __restrict__ zn,    // [B, L, D] bf16
    const float* __restrict__ wh,   // [L, D] f32 (window already applied)
    const float* __restrict__ a,
    float* __restrict__ out)        // [B, L, D] f32
{
  __shared__ float whs[64 * 64];
  __shared__ float znt[127 * 64];
  const int tid = threadIdx.x;
  const int dd = tid & 63, ttg = tid >> 6;
  const int t0 = blockIdx.x * 64, d0 = blockIdx.y * 64, b = blockIdx.z;
  const float expa = expf(a[0]);
  const float smax = 20.7f / expa;   // exp(-smax*expa) ~ 1e-9: tail negligible

  float acc[16];
#pragma unroll
  for (int q = 0; q < 16; ++q) acc[q] = 0.f;

  for (int sb = 0; sb <= t0 + 63; sb += 64) {
    if ((float)sb > smax) break;
    for (int idx = tid; idx < 64 * 64; idx += 256) {
      int ss = idx >> 6, d2 = idx & 63;
      int s = sb + ss;
      whs[idx] = (s < 2048) ? wh[(size_t)s * 1024 + d0 + d2] : 0.f;
    }
    for (int idx = tid; idx < 127 * 64; idx += 256) {
      int uu = idx >> 6, d2 = idx & 63;
      int u = t0 - sb - 63 + uu;
      znt[idx] = (u >= 0) ? b2f(zn[((size_t)b * 2048 + u) * 1024 + d0 + d2]) : 0.f;
    }
    __syncthreads();
#pragma unroll 4
    for (int ss = 0; ss < 64; ++ss) {
      float wv = whs[ss * 64 + dd];
#pragma unroll
      for (int q = 0; q < 16; ++q) {
        int tt = ttg * 16 + q;
        acc[q] += wv * znt[(tt - ss + 63) * 64 + dd];
      }
    }
    __syncthreads();
  }
#pragma unroll
  for (int q = 0; q < 16; ++q) {
    int t = t0 + ttg * 16 + q;
    out[((size_t)b * 2048 + t) * 1024 + d0 + dd] = acc[q];
  }
}

extern "C" void kernel_launch(void* const* d_in, const int* in_sizes, int n_in,
                              void* d_out, int out_size, void* d_ws, size_t ws_size,
                              hipStream_t stream)
{
  const float* z      = (const float*)d_in[0];
  const float* x      = (const float*)d_in[1];
  const float* a      = (const float*)d_in[2];
  const float* pe     = (const float*)d_in[3];
  const float* w_pos1 = (const float*)d_in[4];
  const float* b_pos1 = (const float*)d_in[5];
  const float* w_pos2 = (const float*)d_in[6];
  const float* b_pos2 = (const float*)d_in[7];
  const float* w1     = (const float*)d_in[8];
  const float* b1     = (const float*)d_in[9];
  const float* w2     = (const float*)d_in[10];
  const float* b2     = (const float*)d_in[11];
  const float* w3     = (const float*)d_in[12];
  const float* b3     = (const float*)d_in[13];
  const float* w4     = (const float*)d_in[14];
  const float* b4     = (const float*)d_in[15];
  const float* ln_g   = (const float*)d_in[16];
  const float* ln_b   = (const float*)d_in[17];

  char* ws = (char*)d_ws;
  bf16* pe_bf  = (bf16*)(ws + 0);           //  2048*128
  bf16* wp1_bf = (bf16*)(ws + 524288);      //  1152*128
  bf16* wp2_bf = (bf16*)(ws + 819200);      //  1024*1152
  bf16* w1_bf  = (bf16*)(ws + 3178496);     //  2048*1024
  bf16* w2_bf  = (bf16*)(ws + 7372800);     //  1024*2048
  bf16* w3_bf  = (bf16*)(ws + 11567104);    //  2048*1024
  bf16* w4_bf  = (bf16*)(ws + 15761408);    //  1024*2048
  bf16* h1     = (bf16*)(ws + 19955712);    //  2048*1152
  bf16* zn_bf  = (bf16*)(ws + 24674304);    //  8192*1024 bf16 (dead after conv)
  bf16* x_bf   = (bf16*)(ws + 41451520);    //  8192*1024 bf16 (dead after gemm5)
  float* wh    = (float*)(ws + 58228736);   //  2048*1024 f32
  float* cwhz  = (float*)(ws + 66617344);   //  8192*1024 f32 (dead after gemm6)
  bf16*  x1n   = (bf16*)(ws + 66617344);    //  reuses cwhz region after gemm6
  bf16*  g     = (bf16*)(ws + 100171776);   //  8192*2048 bf16 (g1 then g3)
  float* x1    = (float*)(ws + 24674304);   //  8192*1024 f32, reuses zn_bf+x_bf region
  float* out   = (float*)d_out;

  // 0. convert weights + activations to bf16
  cvt_k<<<  256, 256, 0, stream>>>(pe,     pe_bf,  262144);
  cvt_k<<<  144, 256, 0, stream>>>(w_pos1, wp1_bf, 147456);
  cvt_k<<< 1152, 256, 0, stream>>>(w_pos2, wp2_bf, 1179648);
  cvt_k<<< 2048, 256, 0, stream>>>(w1,     w1_bf,  2097152);
  cvt_k<<< 2048, 256, 0, stream>>>(w2,     w2_bf,  2097152);
  cvt_k<<< 2048, 256, 0, stream>>>(w3,     w3_bf,  2097152);
  cvt_k<<< 2048, 256, 0, stream>>>(w4,     w4_bf,  2097152);
  cvt_k<<< 8192, 256, 0, stream>>>(x,      x_bf,   8388608);

  // 1. zn = LN(z) -> bf16
  ln_k<<<8192, 256, 0, stream>>>(z, zn_bf, ln_g, ln_b);
  // 2. h1 = gelu(pe @ w_pos1^T + b_pos1) -> bf16   [2048, 1152], K=128
  gemm_k<0><<<dim3(9, 16), 256, 0, stream>>>(pe_bf, wp1_bf, b_pos1, h1, nullptr, nullptr, 2048, 1152, 128);
  // 3. wh = window * (h1 @ w_pos2^T + b_pos2) f32  [2048, 1024], K=1152
  gemm_k<1><<<dim3(8, 16), 256, 0, stream>>>(h1, wp2_bf, b_pos2, wh, a, nullptr, 2048, 1024, 1152);
  // 4. cwhz = causal depthwise conv(zn, wh) f32    [4, 2048, 1024]
  conv_k<<<dim3(32, 16, 4), 256, 0, stream>>>(zn_bf, wh, a, cwhz);
  // 5. g1 = gelu(x @ w1^T + b1) -> bf16            [8192, 2048], K=1024
  gemm_k<0><<<dim3(16, 64), 256, 0, stream>>>(x_bf, w1_bf, b1, g, nullptr, nullptr, 8192, 2048, 1024);
  // 6. x1 = (g1 @ w2^T + b2) * cwhz + z   f32      [8192, 1024], K=2048
  gemm_k<2><<<dim3(8, 64), 256, 0, stream>>>(g, w2_bf, b2, x1, cwhz, z, 8192, 1024, 2048);
  // 7. x1n = LN(x1) -> bf16
  ln_k<<<8192, 256, 0, stream>>>(x1, x1n, ln_g, ln_b);
  // 8. g3 = gelu(x1n @ w3^T + b3) -> bf16          [8192, 2048], K=1024
  gemm_k<0><<<dim3(16, 64), 256, 0, stream>>>(x1n, w3_bf, b3, g, nullptr, nullptr, 8192, 2048, 1024);
  // 9. out = (g3 @ w4^T + b4) + x1  f32            [8192, 1024], K=2048
  gemm_k<3><<<dim3(8, 64), 256, 0, stream>>>(g, w4_bf, b4, out, x1, nullptr, 8192, 1024, 2048);
}

// Round 6
// 480.406 us; speedup vs baseline: 1.1705x; 1.0682x over previous
//
#include <hip/hip_runtime.h>
#include <hip/hip_bf16.h>
#include <cmath>

typedef __hip_bfloat16 bf16;
typedef __attribute__((ext_vector_type(8))) short bf16x8;
typedef __attribute__((ext_vector_type(4))) float f32x4;

static __device__ __forceinline__ float b2f(bf16 v) { return __bfloat162float(v); }
static __device__ __forceinline__ bf16 f2b(float v) { return __float2bfloat16(v); }

// async global->LDS, 16B per lane; LDS dst is wave-uniform base + lane*16 (implicit)
static __device__ __forceinline__ void gl2lds16(const bf16* g, bf16* l) {
  __builtin_amdgcn_global_load_lds(
      (const __attribute__((address_space(1))) void*)g,
      (__attribute__((address_space(3))) void*)l, 16, 0, 0);
}

// tanh-form GELU: |err vs erf-form| <~1e-3, far below bf16 rounding of outputs
static __device__ __forceinline__ float gelu_fast(float v) {
  float u = v * (0.7978845608f + 0.0356774081f * v * v);
  float e = __expf(2.f * u);
  return v * (e * __frcp_rn(e + 1.f));   // 0.5*v*(1+tanh(u)) = v*e/(e+1)
}

// ---------------- fused f32 -> bf16 convert for the 7 weight tensors ----------------
// dst regions are contiguous in ws starting at offset 0; each block does 1024 elems.
struct CvtSegs { const float* src[7]; int blk_off[8]; };
__global__ __launch_bounds__(256) void cvt7_k(CvtSegs s, bf16* __restrict__ dst0)
{
  int b = blockIdx.x;
  int seg = 0;
#pragma unroll
  for (int i = 0; i < 6; ++i) seg += (b >= s.blk_off[i + 1]) ? 1 : 0;
  const float* src = s.src[seg] + (size_t)(b - s.blk_off[seg]) * 1024;
  bf16* dst = dst0 + (size_t)b * 1024;
  int idx = threadIdx.x * 4;
  float4 v = *(const float4*)(src + idx);
  union { bf16 bb[4]; ushort4 u; } o;
  o.bb[0] = f2b(v.x); o.bb[1] = f2b(v.y); o.bb[2] = f2b(v.z); o.bb[3] = f2b(v.w);
  *(ushort4*)(dst + idx) = o.u;
}

// ---------------- f32 -> bf16 convert, 4 elems/thread ----------------
__global__ __launch_bounds__(256) void cvt_k(const float* __restrict__ in,
                                             bf16* __restrict__ out, int n)
{
  int idx = (blockIdx.x * 256 + threadIdx.x) * 4;
  if (idx >= n) return;
  float4 v = *(const float4*)(in + idx);
  union { bf16 b[4]; ushort4 u; } o;
  o.b[0] = f2b(v.x); o.b[1] = f2b(v.y); o.b[2] = f2b(v.z); o.b[3] = f2b(v.w);
  *(ushort4*)(out + idx) = o.u;
}

// ---------------- LayerNorm over rows of 1024: f32 in, bf16 out ----------------
__global__ __launch_bounds__(256) void ln_k(const float* __restrict__ X, bf16* __restrict__ Y,
                                            const float* __restrict__ gamma,
                                            const float* __restrict__ beta)
{
  __shared__ float red[16];
  const int row = blockIdx.x, tid = threadIdx.x;
  const float* xr = X + (size_t)row * 1024;
  float v[4], s = 0.f, s2 = 0.f;
#pragma unroll
  for (int i = 0; i < 4; ++i) {
    float xv = xr[tid + i * 256];
    v[i] = xv; s += xv; s2 += xv * xv;
  }
#pragma unroll
  for (int m = 32; m; m >>= 1) { s += __shfl_xor(s, m, 64); s2 += __shfl_xor(s2, m, 64); }
  const int wid = tid >> 6;
  if ((tid & 63) == 0) { red[wid] = s; red[wid + 8] = s2; }
  __syncthreads();
  s  = red[0] + red[1] + red[2] + red[3];
  s2 = red[8] + red[9] + red[10] + red[11];
  const float mu  = s * (1.f / 1024.f);
  const float var = s2 * (1.f / 1024.f) - mu * mu;
  const float rs  = rsqrtf(var + 1e-5f);
#pragma unroll
  for (int i = 0; i < 4; ++i) {
    int c = tid + i * 256;
    Y[(size_t)row * 1024 + c] = f2b((v[i] - mu) * rs * gamma[c] + beta[c]);
  }
}

// ---------------- GEMM: C = A[M,K](bf16) * W[N,K](bf16)^T + bias(f32) ----------------
// 3-stage async pipeline, BK=32, 3 LDS buffers (48 KB), one s_barrier per iter,
// s_waitcnt vmcnt(4) (prefetch for tile k+1 stays in flight across the barrier).
// XOR swizzle (round-3, verified 0 conflicts): slot p holds chunk
// (row=p>>2, kc=(p&3)^((p>>3)&3)); fragment (row ar, quad) at slot ar*4+(quad^((ar>>1)&3)).
// EPI 0: out bf16 = gelu(v)
// EPI 1: out f32  = v * exp(-m * exp(a))            (aux0 = a f32)
// EPI 2: out f32  = v * aux0[m,n] + aux1[m,n]       (aux0 = cwhz f32, aux1 = z f32)
// EPI 3: out f32  = v + aux0[m,n]                   (aux0 = x1 f32)
template<int EPI>
__global__ __launch_bounds__(256, 3) void gemm_k(
    const bf16* __restrict__ A, const bf16* __restrict__ W,
    const float* __restrict__ bias, void* __restrict__ Out,
    const void* __restrict__ aux0, const void* __restrict__ aux1,
    int M, int N, int K)
{
  __shared__ bf16 As[3][128 * 32];
  __shared__ bf16 Bs[3][128 * 32];
  const int tid = threadIdx.x;
  const int wid = tid >> 6, lane = tid & 63;
  const int quad = lane >> 4, l16 = lane & 15;
  const int wm = wid >> 1, wn = wid & 1;
  const int m0 = blockIdx.y * 128, n0 = blockIdx.x * 128;

  f32x4 acc[4][4];
#pragma unroll
  for (int i = 0; i < 4; ++i)
#pragma unroll
    for (int j = 0; j < 4; ++j) acc[i][j] = (f32x4){0.f, 0.f, 0.f, 0.f};

  // staging source pointers (per lane), swizzled
  const bf16 *ga[2], *gb[2];
  int ldso[2];
#pragma unroll
  for (int r = 0; r < 2; ++r) {
    int p = r * 256 + wid * 64 + lane;
    int row = p >> 2;
    int sko = ((p & 3) ^ ((p >> 3) & 3)) << 3;
    ga[r] = A + (size_t)(m0 + row) * K + sko;
    gb[r] = W + (size_t)(n0 + row) * K + sko;
    ldso[r] = (r * 256 + wid * 64) * 8;   // wave-uniform LDS base (elements)
  }
  // fragment LDS offsets
  int apos[4], bpos[4];
#pragma unroll
  for (int i = 0; i < 4; ++i) {
    int ar = wm * 64 + i * 16 + l16;
    apos[i] = (ar * 4 + (quad ^ ((ar >> 1) & 3))) * 8;
    int br = wn * 64 + i * 16 + l16;
    bpos[i] = (br * 4 + (quad ^ ((br >> 1) & 3))) * 8;
  }

  const int niter = K >> 5;   // K multiple of 32, niter >= 4 for all call sites

  // prologue: tiles 0 and 1 -> buffers 0,1 (4 DMA per wave per tile)
#pragma unroll
  for (int t = 0; t < 2; ++t) {
#pragma unroll
    for (int r = 0; r < 2; ++r) {
      gl2lds16(ga[r] + t * 32, &As[t][ldso[r]]);
      gl2lds16(gb[r] + t * 32, &Bs[t][ldso[r]]);
    }
  }

  int cur = 0;                 // buffer of tile k
  for (int k = 0; k < niter; ++k) {
    if (k == niter - 1) { asm volatile("s_waitcnt vmcnt(0)" ::: "memory"); }
    else               { asm volatile("s_waitcnt vmcnt(4)" ::: "memory"); }
    asm volatile("s_barrier" ::: "memory");

    const bf16* as = As[cur];
    const bf16* bs = Bs[cur];
    bf16x8 af[4], bfr[4];
#pragma unroll
    for (int i = 0; i < 4; ++i) af[i]  = *(const bf16x8*)(as + apos[i]);
#pragma unroll
    for (int j = 0; j < 4; ++j) bfr[j] = *(const bf16x8*)(bs + bpos[j]);
    asm volatile("s_waitcnt lgkmcnt(0)" ::: "memory");

    if (k + 2 < niter) {       // prefetch tile k+2 into the buffer tile k-1 used
      int nb = cur + 2; if (nb >= 3) nb -= 3;
#pragma unroll
      for (int r = 0; r < 2; ++r) {
        gl2lds16(ga[r] + (k + 2) * 32, &As[nb][ldso[r]]);
        gl2lds16(gb[r] + (k + 2) * 32, &Bs[nb][ldso[r]]);
      }
    }

#pragma unroll
    for (int i = 0; i < 4; ++i)
#pragma unroll
      for (int j = 0; j < 4; ++j)
        acc[i][j] = __builtin_amdgcn_mfma_f32_16x16x32_bf16(af[i], bfr[j], acc[i][j], 0, 0, 0);

    cur += 1; if (cur == 3) cur = 0;
  }

  float expa = 0.f;
  if (EPI == 1) expa = expf(((const float*)aux0)[0]);

#pragma unroll
  for (int i = 0; i < 4; ++i) {
    const int gm_base = m0 + wm * 64 + i * 16 + quad * 4;
#pragma unroll
    for (int j = 0; j < 4; ++j) {
      const int gn = n0 + wn * 64 + j * 16 + l16;
      const float bv = bias[gn];
#pragma unroll
      for (int r = 0; r < 4; ++r) {
        const int gm = gm_base + r;
        const size_t off = (size_t)gm * N + gn;
        float v = acc[i][j][r] + bv;
        if (EPI == 0) {
          ((bf16*)Out)[off] = f2b(gelu_fast(v));
        } else if (EPI == 1) {
          ((float*)Out)[off] = v * expf(-(float)gm * expa);
        } else if (EPI == 2) {
          ((float*)Out)[off] = v * ((const float*)aux0)[off] + ((const float*)aux1)[off];
        } else { // EPI == 3
          ((float*)Out)[off] = v + ((const float*)aux0)[off];
        }
      }
    }
  }
}

// ---------------- causal depthwise conv: out[b,t,d] = sum_{s<=t} wh[s,d]*zn[b,t-s,d] ----------------
__global__ __launch_bounds__(256) void conv_k(
    const bf16* __restrict__ zn,    // [B, L, D] bf16
    const float* __restrict__ wh,   // [L, D] f32 (window already applied)
    const float* __restrict__ a,
    float* __restrict__ out)        // [B, L, D] f32
{
  __shared__ float whs[64 * 64];
  __shared__ float znt[127 * 64];
  const int tid = threadIdx.x;
  const int dd = tid & 63, ttg = tid >> 6;
  const int t0 = blockIdx.x * 64, d0 = blockIdx.y * 64, b = blockIdx.z;
  const float expa = expf(a[0]);
  const float smax = 20.7f / expa;   // exp(-smax*expa) ~ 1e-9: tail negligible

  float acc[16];
#pragma unroll
  for (int q = 0; q < 16; ++q) acc[q] = 0.f;

  for (int sb = 0; sb <= t0 + 63; sb += 64) {
    if ((float)sb > smax) break;
    for (int idx = tid; idx < 64 * 64; idx += 256) {
      int ss = idx >> 6, d2 = idx & 63;
      int s = sb + ss;
      whs[idx] = (s < 2048) ? wh[(size_t)s * 1024 + d0 + d2] : 0.f;
    }
    for (int idx = tid; idx < 127 * 64; idx += 256) {
      int uu = idx >> 6, d2 = idx & 63;
      int u = t0 - sb - 63 + uu;
      znt[idx] = (u >= 0) ? b2f(zn[((size_t)b * 2048 + u) * 1024 + d0 + d2]) : 0.f;
    }
    __syncthreads();
#pragma unroll 4
    for (int ss = 0; ss < 64; ++ss) {
      float wv = whs[ss * 64 + dd];
#pragma unroll
      for (int q = 0; q < 16; ++q) {
        int tt = ttg * 16 + q;
        acc[q] += wv * znt[(tt - ss + 63) * 64 + dd];
      }
    }
    __syncthreads();
  }
#pragma unroll
  for (int q = 0; q < 16; ++q) {
    int t = t0 + ttg * 16 + q;
    out[((size_t)b * 2048 + t) * 1024 + d0 + dd] = acc[q];
  }
}

extern "C" void kernel_launch(void* const* d_in, const int* in_sizes, int n_in,
                              void* d_out, int out_size, void* d_ws, size_t ws_size,
                              hipStream_t stream)
{
  const float* z      = (const float*)d_in[0];
  const float* x      = (const float*)d_in[1];
  const float* a      = (const float*)d_in[2];
  const float* pe     = (const float*)d_in[3];
  const float* w_pos1 = (const float*)d_in[4];
  const float* b_pos1 = (const float*)d_in[5];
  const float* w_pos2 = (const float*)d_in[6];
  const float* b_pos2 = (const float*)d_in[7];
  const float* w1     = (const float*)d_in[8];
  const float* b1     = (const float*)d_in[9];
  const float* w2     = (const float*)d_in[10];
  const float* b2     = (const float*)d_in[11];
  const float* w3     = (const float*)d_in[12];
  const float* b3     = (const float*)d_in[13];
  const float* w4     = (const float*)d_in[14];
  const float* b4     = (const float*)d_in[15];
  const float* ln_g   = (const float*)d_in[16];
  const float* ln_b   = (const float*)d_in[17];

  char* ws = (char*)d_ws;
  bf16* pe_bf  = (bf16*)(ws + 0);           //  2048*128
  bf16* wp1_bf = (bf16*)(ws + 524288);      //  1152*128
  bf16* wp2_bf = (bf16*)(ws + 819200);      //  1024*1152
  bf16* w1_bf  = (bf16*)(ws + 3178496);     //  2048*1024
  bf16* w2_bf  = (bf16*)(ws + 7372800);     //  1024*2048
  bf16* w3_bf  = (bf16*)(ws + 11567104);    //  2048*1024
  bf16* w4_bf  = (bf16*)(ws + 15761408);    //  1024*2048
  bf16* h1     = (bf16*)(ws + 19955712);    //  2048*1152
  bf16* zn_bf  = (bf16*)(ws + 24674304);    //  8192*1024 bf16 (dead after conv)
  bf16* x_bf   = (bf16*)(ws + 41451520);    //  8192*1024 bf16 (dead after gemm5)
  float* wh    = (float*)(ws + 58228736);   //  2048*1024 f32
  float* cwhz  = (float*)(ws + 66617344);   //  8192*1024 f32 (dead after gemm6)
  bf16*  x1n   = (bf16*)(ws + 66617344);    //  reuses cwhz region after gemm6
  bf16*  g     = (bf16*)(ws + 100171776);   //  8192*2048 bf16 (g1 then g3)
  float* x1    = (float*)(ws + 24674304);   //  8192*1024 f32, reuses zn_bf+x_bf region
  float* out   = (float*)d_out;

  // 0a. fused weight converts (dst contiguous at ws+0)
  CvtSegs segs;
  segs.src[0] = pe;  segs.src[1] = w_pos1; segs.src[2] = w_pos2;
  segs.src[3] = w1;  segs.src[4] = w2;     segs.src[5] = w3; segs.src[6] = w4;
  int bo[8] = {0, 256, 400, 1552, 3600, 5648, 7696, 9744};
  for (int i = 0; i < 8; ++i) segs.blk_off[i] = bo[i];
  cvt7_k<<<9744, 256, 0, stream>>>(segs, (bf16*)ws);
  // 0b. x -> bf16
  cvt_k<<<8192, 256, 0, stream>>>(x, x_bf, 8388608);

  // 1. zn = LN(z) -> bf16
  ln_k<<<8192, 256, 0, stream>>>(z, zn_bf, ln_g, ln_b);
  // 2. h1 = gelu(pe @ w_pos1^T + b_pos1) -> bf16   [2048, 1152], K=128
  gemm_k<0><<<dim3(9, 16), 256, 0, stream>>>(pe_bf, wp1_bf, b_pos1, h1, nullptr, nullptr, 2048, 1152, 128);
  // 3. wh = window * (h1 @ w_pos2^T + b_pos2) f32  [2048, 1024], K=1152
  gemm_k<1><<<dim3(8, 16), 256, 0, stream>>>(h1, wp2_bf, b_pos2, wh, a, nullptr, 2048, 1024, 1152);
  // 4. cwhz = causal depthwise conv(zn, wh) f32    [4, 2048, 1024]
  conv_k<<<dim3(32, 16, 4), 256, 0, stream>>>(zn_bf, wh, a, cwhz);
  // 5. g1 = gelu(x @ w1^T + b1) -> bf16            [8192, 2048], K=1024
  gemm_k<0><<<dim3(16, 64), 256, 0, stream>>>(x_bf, w1_bf, b1, g, nullptr, nullptr, 8192, 2048, 1024);
  // 6. x1 = (g1 @ w2^T + b2) * cwhz + z   f32      [8192, 1024], K=2048
  gemm_k<2><<<dim3(8, 64), 256, 0, stream>>>(g, w2_bf, b2, x1, cwhz, z, 8192, 1024, 2048);
  // 7. x1n = LN(x1) -> bf16
  ln_k<<<8192, 256, 0, stream>>>(x1, x1n, ln_g, ln_b);
  // 8. g3 = gelu(x1n @ w3^T + b3) -> bf16          [8192, 2048], K=1024
  gemm_k<0><<<dim3(16, 64), 256, 0, stream>>>(x1n, w3_bf, b3, g, nullptr, nullptr, 8192, 2048, 1024);
  // 9. out = (g3 @ w4^T + b4) + x1  f32            [8192, 1024], K=2048
  gemm_k<3><<<dim3(8, 64), 256, 0, stream>>>(g, w4_bf, b4, out, x1, nullptr, 8192, 1024, 2048);
}

// Round 7
// 479.738 us; speedup vs baseline: 1.1721x; 1.0014x over previous
//
#include <hip/hip_runtime.h>
#include <hip/hip_bf16.h>
#include <cmath>

typedef __hip_bfloat16 bf16;
typedef __attribute__((ext_vector_type(8))) short bf16x8;
typedef __attribute__((ext_vector_type(4))) float f32x4;

static __device__ __forceinline__ float b2f(bf16 v) { return __bfloat162float(v); }
static __device__ __forceinline__ bf16 f2b(float v) { return __float2bfloat16(v); }

// async global->LDS, 16B per lane; LDS dst is wave-uniform base + lane*16 (implicit)
static __device__ __forceinline__ void gl2lds16(const bf16* g, bf16* l) {
  __builtin_amdgcn_global_load_lds(
      (const __attribute__((address_space(1))) void*)g,
      (__attribute__((address_space(3))) void*)l, 16, 0, 0);
}

// tanh-form GELU: |err vs erf-form| <~1e-3, far below bf16 rounding of outputs
static __device__ __forceinline__ float gelu_fast(float v) {
  float u = v * (0.7978845608f + 0.0356774081f * v * v);
  float e = __expf(2.f * u);
  return v * (e * __frcp_rn(e + 1.f));   // 0.5*v*(1+tanh(u)) = v*e/(e+1)
}

// ---------------- fused f32 -> bf16 convert for the 7 weight tensors ----------------
struct CvtSegs { const float* src[7]; int blk_off[8]; };
__global__ __launch_bounds__(256) void cvt7_k(CvtSegs s, bf16* __restrict__ dst0)
{
  int b = blockIdx.x;
  int seg = 0;
#pragma unroll
  for (int i = 0; i < 6; ++i) seg += (b >= s.blk_off[i + 1]) ? 1 : 0;
  const float* src = s.src[seg] + (size_t)(b - s.blk_off[seg]) * 1024;
  bf16* dst = dst0 + (size_t)b * 1024;
  int idx = threadIdx.x * 4;
  float4 v = *(const float4*)(src + idx);
  union { bf16 bb[4]; ushort4 u; } o;
  o.bb[0] = f2b(v.x); o.bb[1] = f2b(v.y); o.bb[2] = f2b(v.z); o.bb[3] = f2b(v.w);
  *(ushort4*)(dst + idx) = o.u;
}

// ---------------- f32 -> bf16 convert, 4 elems/thread ----------------
__global__ __launch_bounds__(256) void cvt_k(const float* __restrict__ in,
                                             bf16* __restrict__ out, int n)
{
  int idx = (blockIdx.x * 256 + threadIdx.x) * 4;
  if (idx >= n) return;
  float4 v = *(const float4*)(in + idx);
  union { bf16 b[4]; ushort4 u; } o;
  o.b[0] = f2b(v.x); o.b[1] = f2b(v.y); o.b[2] = f2b(v.z); o.b[3] = f2b(v.w);
  *(ushort4*)(out + idx) = o.u;
}

// ---------------- LayerNorm over rows of 1024: f32 in, bf16 out ----------------
__global__ __launch_bounds__(256) void ln_k(const float* __restrict__ X, bf16* __restrict__ Y,
                                            const float* __restrict__ gamma,
                                            const float* __restrict__ beta)
{
  __shared__ float red[16];
  const int row = blockIdx.x, tid = threadIdx.x;
  const float* xr = X + (size_t)row * 1024;
  float v[4], s = 0.f, s2 = 0.f;
#pragma unroll
  for (int i = 0; i < 4; ++i) {
    float xv = xr[tid + i * 256];
    v[i] = xv; s += xv; s2 += xv * xv;
  }
#pragma unroll
  for (int m = 32; m; m >>= 1) { s += __shfl_xor(s, m, 64); s2 += __shfl_xor(s2, m, 64); }
  const int wid = tid >> 6;
  if ((tid & 63) == 0) { red[wid] = s; red[wid + 8] = s2; }
  __syncthreads();
  s  = red[0] + red[1] + red[2] + red[3];
  s2 = red[8] + red[9] + red[10] + red[11];
  const float mu  = s * (1.f / 1024.f);
  const float var = s2 * (1.f / 1024.f) - mu * mu;
  const float rs  = rsqrtf(var + 1e-5f);
#pragma unroll
  for (int i = 0; i < 4; ++i) {
    int c = tid + i * 256;
    Y[(size_t)row * 1024 + c] = f2b((v[i] - mu) * rs * gamma[c] + beta[c]);
  }
}

// ---------------- GEMM: C = A[M,K](bf16) * W[N,K](bf16)^T + bias(f32) ----------------
// 3-stage async pipeline, BK=32, 3 LDS buffers (48 KB), one s_barrier per iter,
// s_waitcnt vmcnt(4) (prefetch for tile k+1 stays in flight across the barrier).
// XOR swizzle (verified 0 conflicts): slot p holds chunk
// (row=p>>2, kc=(p&3)^((p>>3)&3)); fragment (row ar, quad) at slot ar*4+(quad^((ar>>1)&3)).
template<int EPI>
__global__ __launch_bounds__(256, 3) void gemm_k(
    const bf16* __restrict__ A, const bf16* __restrict__ W,
    const float* __restrict__ bias, void* __restrict__ Out,
    const void* __restrict__ aux0, const void* __restrict__ aux1,
    int M, int N, int K)
{
  __shared__ bf16 As[3][128 * 32];
  __shared__ bf16 Bs[3][128 * 32];
  const int tid = threadIdx.x;
  const int wid = tid >> 6, lane = tid & 63;
  const int quad = lane >> 4, l16 = lane & 15;
  const int wm = wid >> 1, wn = wid & 1;
  const int m0 = blockIdx.y * 128, n0 = blockIdx.x * 128;

  f32x4 acc[4][4];
#pragma unroll
  for (int i = 0; i < 4; ++i)
#pragma unroll
    for (int j = 0; j < 4; ++j) acc[i][j] = (f32x4){0.f, 0.f, 0.f, 0.f};

  const bf16 *ga[2], *gb[2];
  int ldso[2];
#pragma unroll
  for (int r = 0; r < 2; ++r) {
    int p = r * 256 + wid * 64 + lane;
    int row = p >> 2;
    int sko = ((p & 3) ^ ((p >> 3) & 3)) << 3;
    ga[r] = A + (size_t)(m0 + row) * K + sko;
    gb[r] = W + (size_t)(n0 + row) * K + sko;
    ldso[r] = (r * 256 + wid * 64) * 8;
  }
  int apos[4], bpos[4];
#pragma unroll
  for (int i = 0; i < 4; ++i) {
    int ar = wm * 64 + i * 16 + l16;
    apos[i] = (ar * 4 + (quad ^ ((ar >> 1) & 3))) * 8;
    int br = wn * 64 + i * 16 + l16;
    bpos[i] = (br * 4 + (quad ^ ((br >> 1) & 3))) * 8;
  }

  const int niter = K >> 5;

#pragma unroll
  for (int t = 0; t < 2; ++t) {
#pragma unroll
    for (int r = 0; r < 2; ++r) {
      gl2lds16(ga[r] + t * 32, &As[t][ldso[r]]);
      gl2lds16(gb[r] + t * 32, &Bs[t][ldso[r]]);
    }
  }

  int cur = 0;
  for (int k = 0; k < niter; ++k) {
    if (k == niter - 1) { asm volatile("s_waitcnt vmcnt(0)" ::: "memory"); }
    else               { asm volatile("s_waitcnt vmcnt(4)" ::: "memory"); }
    asm volatile("s_barrier" ::: "memory");

    const bf16* as = As[cur];
    const bf16* bs = Bs[cur];
    bf16x8 af[4], bfr[4];
#pragma unroll
    for (int i = 0; i < 4; ++i) af[i]  = *(const bf16x8*)(as + apos[i]);
#pragma unroll
    for (int j = 0; j < 4; ++j) bfr[j] = *(const bf16x8*)(bs + bpos[j]);
    asm volatile("s_waitcnt lgkmcnt(0)" ::: "memory");

    if (k + 2 < niter) {
      int nb = cur + 2; if (nb >= 3) nb -= 3;
#pragma unroll
      for (int r = 0; r < 2; ++r) {
        gl2lds16(ga[r] + (k + 2) * 32, &As[nb][ldso[r]]);
        gl2lds16(gb[r] + (k + 2) * 32, &Bs[nb][ldso[r]]);
      }
    }

#pragma unroll
    for (int i = 0; i < 4; ++i)
#pragma unroll
      for (int j = 0; j < 4; ++j)
        acc[i][j] = __builtin_amdgcn_mfma_f32_16x16x32_bf16(af[i], bfr[j], acc[i][j], 0, 0, 0);

    cur += 1; if (cur == 3) cur = 0;
  }

  float expa = 0.f;
  if (EPI == 1) expa = expf(((const float*)aux0)[0]);

#pragma unroll
  for (int i = 0; i < 4; ++i) {
    const int gm_base = m0 + wm * 64 + i * 16 + quad * 4;
#pragma unroll
    for (int j = 0; j < 4; ++j) {
      const int gn = n0 + wn * 64 + j * 16 + l16;
      const float bv = bias[gn];
#pragma unroll
      for (int r = 0; r < 4; ++r) {
        const int gm = gm_base + r;
        const size_t off = (size_t)gm * N + gn;
        float v = acc[i][j][r] + bv;
        if (EPI == 0) {
          ((bf16*)Out)[off] = f2b(gelu_fast(v));
        } else if (EPI == 1) {
          ((float*)Out)[off] = v * expf(-(float)gm * expa);
        } else if (EPI == 2) {
          ((float*)Out)[off] = v * ((const float*)aux0)[off] + ((const float*)aux1)[off];
        } else { // EPI == 3
          ((float*)Out)[off] = v + ((const float*)aux0)[off];
        }
      }
    }
  }
}

// ---------------- causal depthwise conv: out[b,t,d] = sum_{s<=t} wh[s,d]*zn[b,t-s,d] ----------------
// Sliding-window register reuse: each thread holds 16 t-outputs for one d; per
// tap s it does 2 LDS reads (1 wh + 1 new zn element) + 16 FMAs; the 16-deep
// window shifts by register renaming (ss-loop fully unrolled).
__global__ __launch_bounds__(256) void conv_k(
    const bf16* __restrict__ zn,    // [B, L, D] bf16
    const float* __restrict__ wh,   // [L, D] f32 (window already applied)
    const float* __restrict__ a,
    float* __restrict__ out)        // [B, L, D] f32
{
  __shared__ float whs[64 * 64];
  __shared__ float znt[128 * 64];   // row r holds u = t0 - sb - 64 + r
  const int tid = threadIdx.x;
  const int dd = tid & 63, ttg = tid >> 6;
  const int t0 = blockIdx.x * 64, d0 = blockIdx.y * 64, b = blockIdx.z;
  const float expa = expf(a[0]);
  const float smax = 20.7f / expa;   // exp(-smax*expa) ~ 1e-9: tail negligible

  float acc[16];
#pragma unroll
  for (int q = 0; q < 16; ++q) acc[q] = 0.f;

  for (int sb = 0; sb <= t0 + 63; sb += 64) {
    if ((float)sb > smax) break;
    for (int idx = tid; idx < 64 * 64; idx += 256) {
      int ss = idx >> 6, d2 = idx & 63;
      int s = sb + ss;
      whs[idx] = (s < 2048) ? wh[(size_t)s * 1024 + d0 + d2] : 0.f;
    }
    for (int idx = tid; idx < 128 * 64; idx += 256) {
      int r = idx >> 6, d2 = idx & 63;
      int u = t0 - sb - 64 + r;
      znt[idx] = (u >= 0) ? b2f(zn[((size_t)b * 2048 + u) * 1024 + d0 + d2]) : 0.f;
    }
    __syncthreads();

    // window: win[q] = znt row (ttg*16 + q - ss + 64), for current ss
    float win[16];
#pragma unroll
    for (int q = 0; q < 16; ++q) win[q] = znt[(ttg * 16 + q + 64) * 64 + dd];

#pragma unroll
    for (int ss = 0; ss < 64; ++ss) {
      float wv = whs[ss * 64 + dd];
#pragma unroll
      for (int q = 0; q < 16; ++q) acc[q] += wv * win[q];
      if (ss < 63) {
#pragma unroll
        for (int q = 15; q >= 1; --q) win[q] = win[q - 1];
        win[0] = znt[(ttg * 16 + 63 - ss) * 64 + dd];
      }
    }
    __syncthreads();
  }
#pragma unroll
  for (int q = 0; q < 16; ++q) {
    int t = t0 + ttg * 16 + q;
    out[((size_t)b * 2048 + t) * 1024 + d0 + dd] = acc[q];
  }
}

extern "C" void kernel_launch(void* const* d_in, const int* in_sizes, int n_in,
                              void* d_out, int out_size, void* d_ws, size_t ws_size,
                              hipStream_t stream)
{
  const float* z      = (const float*)d_in[0];
  const float* x      = (const float*)d_in[1];
  const float* a      = (const float*)d_in[2];
  const float* pe     = (const float*)d_in[3];
  const float* w_pos1 = (const float*)d_in[4];
  const float* b_pos1 = (const float*)d_in[5];
  const float* w_pos2 = (const float*)d_in[6];
  const float* b_pos2 = (const float*)d_in[7];
  const float* w1     = (const float*)d_in[8];
  const float* b1     = (const float*)d_in[9];
  const float* w2     = (const float*)d_in[10];
  const float* b2     = (const float*)d_in[11];
  const float* w3     = (const float*)d_in[12];
  const float* b3     = (const float*)d_in[13];
  const float* w4     = (const float*)d_in[14];
  const float* b4     = (const float*)d_in[15];
  const float* ln_g   = (const float*)d_in[16];
  const float* ln_b   = (const float*)d_in[17];

  char* ws = (char*)d_ws;
  bf16* pe_bf  = (bf16*)(ws + 0);           //  2048*128
  bf16* wp1_bf = (bf16*)(ws + 524288);      //  1152*128
  bf16* wp2_bf = (bf16*)(ws + 819200);      //  1024*1152
  bf16* w1_bf  = (bf16*)(ws + 3178496);     //  2048*1024
  bf16* w2_bf  = (bf16*)(ws + 7372800);     //  1024*2048
  bf16* w3_bf  = (bf16*)(ws + 11567104);    //  2048*1024
  bf16* w4_bf  = (bf16*)(ws + 15761408);    //  1024*2048
  bf16* h1     = (bf16*)(ws + 19955712);    //  2048*1152
  bf16* zn_bf  = (bf16*)(ws + 24674304);    //  8192*1024 bf16 (dead after conv)
  bf16* x_bf   = (bf16*)(ws + 41451520);    //  8192*1024 bf16 (dead after gemm5)
  float* wh    = (float*)(ws + 58228736);   //  2048*1024 f32
  float* cwhz  = (float*)(ws + 66617344);   //  8192*1024 f32 (dead after gemm6)
  bf16*  x1n   = (bf16*)(ws + 66617344);    //  reuses cwhz region after gemm6
  bf16*  g     = (bf16*)(ws + 100171776);   //  8192*2048 bf16 (g1 then g3)
  float* x1    = (float*)(ws + 24674304);   //  8192*1024 f32, reuses zn_bf+x_bf region
  float* out   = (float*)d_out;

  // 0a. fused weight converts (dst contiguous at ws+0)
  CvtSegs segs;
  segs.src[0] = pe;  segs.src[1] = w_pos1; segs.src[2] = w_pos2;
  segs.src[3] = w1;  segs.src[4] = w2;     segs.src[5] = w3; segs.src[6] = w4;
  int bo[8] = {0, 256, 400, 1552, 3600, 5648, 7696, 9744};
  for (int i = 0; i < 8; ++i) segs.blk_off[i] = bo[i];
  cvt7_k<<<9744, 256, 0, stream>>>(segs, (bf16*)ws);
  // 0b. x -> bf16
  cvt_k<<<8192, 256, 0, stream>>>(x, x_bf, 8388608);

  // 1. zn = LN(z) -> bf16
  ln_k<<<8192, 256, 0, stream>>>(z, zn_bf, ln_g, ln_b);
  // 2. h1 = gelu(pe @ w_pos1^T + b_pos1) -> bf16   [2048, 1152], K=128
  gemm_k<0><<<dim3(9, 16), 256, 0, stream>>>(pe_bf, wp1_bf, b_pos1, h1, nullptr, nullptr, 2048, 1152, 128);
  // 3. wh = window * (h1 @ w_pos2^T + b_pos2) f32  [2048, 1024], K=1152
  gemm_k<1><<<dim3(8, 16), 256, 0, stream>>>(h1, wp2_bf, b_pos2, wh, a, nullptr, 2048, 1024, 1152);
  // 4. cwhz = causal depthwise conv(zn, wh) f32    [4, 2048, 1024]
  conv_k<<<dim3(32, 16, 4), 256, 0, stream>>>(zn_bf, wh, a, cwhz);
  // 5. g1 = gelu(x @ w1^T + b1) -> bf16            [8192, 2048], K=1024
  gemm_k<0><<<dim3(16, 64), 256, 0, stream>>>(x_bf, w1_bf, b1, g, nullptr, nullptr, 8192, 2048, 1024);
  // 6. x1 = (g1 @ w2^T + b2) * cwhz + z   f32      [8192, 1024], K=2048
  gemm_k<2><<<dim3(8, 64), 256, 0, stream>>>(g, w2_bf, b2, x1, cwhz, z, 8192, 1024, 2048);
  // 7. x1n = LN(x1) -> bf16
  ln_k<<<8192, 256, 0, stream>>>(x1, x1n, ln_g, ln_b);
  // 8. g3 = gelu(x1n @ w3^T + b3) -> bf16          [8192, 2048], K=1024
  gemm_k<0><<<dim3(16, 64), 256, 0, stream>>>(x1n, w3_bf, b3, g, nullptr, nullptr, 8192, 2048, 1024);
  // 9. out = (g3 @ w4^T + b4) + x1  f32            [8192, 1024], K=2048
  gemm_k<3><<<dim3(8, 64), 256, 0, stream>>>(g, w4_bf, b4, out, x1, nullptr, 8192, 1024, 2048);
}

// Round 8
// 444.898 us; speedup vs baseline: 1.2639x; 1.0783x over previous
//
#include <hip/hip_runtime.h>
#include <hip/hip_bf16.h>
#include <cmath>

typedef __hip_bfloat16 bf16;
typedef __attribute__((ext_vector_type(8))) short bf16x8;
typedef __attribute__((ext_vector_type(4))) float f32x4;

static __device__ __forceinline__ float b2f(bf16 v) { return __bfloat162float(v); }
static __device__ __forceinline__ bf16 f2b(float v) { return __float2bfloat16(v); }
static __device__ __forceinline__ float us2f(unsigned short u) {
  return __uint_as_float(((unsigned)u) << 16);
}

static __device__ __forceinline__ void gl2lds16(const bf16* g, bf16* l) {
  __builtin_amdgcn_global_load_lds(
      (const __attribute__((address_space(1))) void*)g,
      (__attribute__((address_space(3))) void*)l, 16, 0, 0);
}

// tanh-form GELU: |err vs erf-form| <~1e-3, far below bf16 rounding of outputs
static __device__ __forceinline__ float gelu_fast(float v) {
  float u = v * (0.7978845608f + 0.0356774081f * v * v);
  float e = __expf(2.f * u);
  return v * (e * __frcp_rn(e + 1.f));
}

// ---------------- fused f32 -> bf16 convert for the 7 weight tensors ----------------
struct CvtSegs { const float* src[7]; int blk_off[8]; };
__global__ __launch_bounds__(256) void cvt7_k(CvtSegs s, bf16* __restrict__ dst0)
{
  int b = blockIdx.x;
  int seg = 0;
#pragma unroll
  for (int i = 0; i < 6; ++i) seg += (b >= s.blk_off[i + 1]) ? 1 : 0;
  const float* src = s.src[seg] + (size_t)(b - s.blk_off[seg]) * 1024;
  bf16* dst = dst0 + (size_t)b * 1024;
  int idx = threadIdx.x * 4;
  float4 v = *(const float4*)(src + idx);
  union { bf16 bb[4]; ushort4 u; } o;
  o.bb[0] = f2b(v.x); o.bb[1] = f2b(v.y); o.bb[2] = f2b(v.z); o.bb[3] = f2b(v.w);
  *(ushort4*)(dst + idx) = o.u;
}

__global__ __launch_bounds__(256) void cvt_k(const float* __restrict__ in,
                                             bf16* __restrict__ out, int n)
{
  int idx = (blockIdx.x * 256 + threadIdx.x) * 4;
  if (idx >= n) return;
  float4 v = *(const float4*)(in + idx);
  union { bf16 b[4]; ushort4 u; } o;
  o.b[0] = f2b(v.x); o.b[1] = f2b(v.y); o.b[2] = f2b(v.z); o.b[3] = f2b(v.w);
  *(ushort4*)(out + idx) = o.u;
}

// ---------------- LayerNorm over rows of 1024: f32 in, bf16 out ----------------
__global__ __launch_bounds__(256) void ln_k(const float* __restrict__ X, bf16* __restrict__ Y,
                                            const float* __restrict__ gamma,
                                            const float* __restrict__ beta)
{
  __shared__ float red[16];
  const int row = blockIdx.x, tid = threadIdx.x;
  float4 v = *(const float4*)(X + (size_t)row * 1024 + tid * 4);
  float s  = v.x + v.y + v.z + v.w;
  float s2 = v.x * v.x + v.y * v.y + v.z * v.z + v.w * v.w;
#pragma unroll
  for (int m = 32; m; m >>= 1) { s += __shfl_xor(s, m, 64); s2 += __shfl_xor(s2, m, 64); }
  const int wid = tid >> 6;
  if ((tid & 63) == 0) { red[wid] = s; red[wid + 8] = s2; }
  __syncthreads();
  s  = red[0] + red[1] + red[2] + red[3];
  s2 = red[8] + red[9] + red[10] + red[11];
  const float mu  = s * (1.f / 1024.f);
  const float var = s2 * (1.f / 1024.f) - mu * mu;
  const float rs  = rsqrtf(var + 1e-5f);
  float4 g = *(const float4*)(gamma + tid * 4);
  float4 bt = *(const float4*)(beta + tid * 4);
  union { bf16 b[4]; ushort4 u; } o;
  o.b[0] = f2b((v.x - mu) * rs * g.x + bt.x);
  o.b[1] = f2b((v.y - mu) * rs * g.y + bt.y);
  o.b[2] = f2b((v.z - mu) * rs * g.z + bt.z);
  o.b[3] = f2b((v.w - mu) * rs * g.w + bt.w);
  *(ushort4*)(Y + (size_t)row * 1024 + tid * 4) = o.u;
}

// ================= GEMM 128x128 (4 waves) — used for small steps 2,3 =================
template<int EPI>
__global__ __launch_bounds__(256, 3) void gemm_k(
    const bf16* __restrict__ A, const bf16* __restrict__ W,
    const float* __restrict__ bias, void* __restrict__ Out,
    const void* __restrict__ aux0, const void* __restrict__ aux1,
    int M, int N, int K)
{
  __shared__ bf16 As[3][128 * 32];
  __shared__ bf16 Bs[3][128 * 32];
  const int tid = threadIdx.x;
  const int wid = tid >> 6, lane = tid & 63;
  const int quad = lane >> 4, l16 = lane & 15;
  const int wm = wid >> 1, wn = wid & 1;
  const int m0 = blockIdx.y * 128, n0 = blockIdx.x * 128;

  f32x4 acc[4][4];
#pragma unroll
  for (int i = 0; i < 4; ++i)
#pragma unroll
    for (int j = 0; j < 4; ++j) acc[i][j] = (f32x4){0.f, 0.f, 0.f, 0.f};

  const bf16 *ga[2], *gb[2];
  int ldso[2];
#pragma unroll
  for (int r = 0; r < 2; ++r) {
    int p = r * 256 + wid * 64 + lane;
    int row = p >> 2;
    int sko = ((p & 3) ^ ((p >> 3) & 3)) << 3;
    ga[r] = A + (size_t)(m0 + row) * K + sko;
    gb[r] = W + (size_t)(n0 + row) * K + sko;
    ldso[r] = (r * 256 + wid * 64) * 8;
  }
  int apos[4], bpos[4];
#pragma unroll
  for (int i = 0; i < 4; ++i) {
    int ar = wm * 64 + i * 16 + l16;
    apos[i] = (ar * 4 + (quad ^ ((ar >> 1) & 3))) * 8;
    int br = wn * 64 + i * 16 + l16;
    bpos[i] = (br * 4 + (quad ^ ((br >> 1) & 3))) * 8;
  }

  const int niter = K >> 5;
#pragma unroll
  for (int t = 0; t < 2; ++t)
#pragma unroll
    for (int r = 0; r < 2; ++r) {
      gl2lds16(ga[r] + t * 32, &As[t][ldso[r]]);
      gl2lds16(gb[r] + t * 32, &Bs[t][ldso[r]]);
    }

  int cur = 0;
  for (int k = 0; k < niter; ++k) {
    if (k == niter - 1) { asm volatile("s_waitcnt vmcnt(0)" ::: "memory"); }
    else               { asm volatile("s_waitcnt vmcnt(4)" ::: "memory"); }
    asm volatile("s_barrier" ::: "memory");

    const bf16* as = As[cur];
    const bf16* bs = Bs[cur];
    bf16x8 af[4], bfr[4];
#pragma unroll
    for (int i = 0; i < 4; ++i) af[i]  = *(const bf16x8*)(as + apos[i]);
#pragma unroll
    for (int j = 0; j < 4; ++j) bfr[j] = *(const bf16x8*)(bs + bpos[j]);
    asm volatile("s_waitcnt lgkmcnt(0)" ::: "memory");

    if (k + 2 < niter) {
      int nb = cur + 2; if (nb >= 3) nb -= 3;
#pragma unroll
      for (int r = 0; r < 2; ++r) {
        gl2lds16(ga[r] + (k + 2) * 32, &As[nb][ldso[r]]);
        gl2lds16(gb[r] + (k + 2) * 32, &Bs[nb][ldso[r]]);
      }
    }
#pragma unroll
    for (int i = 0; i < 4; ++i)
#pragma unroll
      for (int j = 0; j < 4; ++j)
        acc[i][j] = __builtin_amdgcn_mfma_f32_16x16x32_bf16(af[i], bfr[j], acc[i][j], 0, 0, 0);
    cur += 1; if (cur == 3) cur = 0;
  }

  float expa = 0.f;
  if (EPI == 1) expa = expf(((const float*)aux0)[0]);
#pragma unroll
  for (int i = 0; i < 4; ++i) {
    const int gm_base = m0 + wm * 64 + i * 16 + quad * 4;
#pragma unroll
    for (int j = 0; j < 4; ++j) {
      const int gn = n0 + wn * 64 + j * 16 + l16;
      const float bv = bias[gn];
#pragma unroll
      for (int r = 0; r < 4; ++r) {
        const int gm = gm_base + r;
        const size_t off = (size_t)gm * N + gn;
        float v = acc[i][j][r] + bv;
        if (EPI == 0) ((bf16*)Out)[off] = f2b(gelu_fast(v));
        else if (EPI == 1) ((float*)Out)[off] = v * expf(-(float)gm * expa);
        else if (EPI == 2) ((float*)Out)[off] = v * ((const float*)aux0)[off] + ((const float*)aux1)[off];
        else ((float*)Out)[off] = v + ((const float*)aux0)[off];
      }
    }
  }
}

// ================= GEMM 128m x 256n (4 waves, 64x128 per wave) — big steps =================
// 3-stage async, BK=32. Staged bytes per output halve on the N-reuse side; 32 MFMA
// per wave-iter; 6 DMA per thread per tile (vmcnt(6) steady-state).
template<int EPI>
__global__ __launch_bounds__(256, 2) void gemm256_k(
    const bf16* __restrict__ A, const bf16* __restrict__ W,
    const float* __restrict__ bias, void* __restrict__ Out,
    const void* __restrict__ aux0, const void* __restrict__ aux1,
    int M, int N, int K)
{
  __shared__ bf16 As[3][128 * 32];
  __shared__ bf16 Bs[3][256 * 32];
  const int tid = threadIdx.x;
  const int wid = tid >> 6, lane = tid & 63;
  const int quad = lane >> 4, l16 = lane & 15;
  const int wm = wid >> 1, wn = wid & 1;
  const int m0 = blockIdx.y * 128, n0 = blockIdx.x * 256;

  f32x4 acc[4][8];
#pragma unroll
  for (int i = 0; i < 4; ++i)
#pragma unroll
    for (int j = 0; j < 8; ++j) acc[i][j] = (f32x4){0.f, 0.f, 0.f, 0.f};

  const bf16 *ga[2], *gb[4];
  int ldsoA[2], ldsoB[4];
#pragma unroll
  for (int r = 0; r < 2; ++r) {
    int p = r * 256 + tid;
    int row = p >> 2;
    int sko = ((p & 3) ^ ((p >> 3) & 3)) << 3;
    ga[r] = A + (size_t)(m0 + row) * K + sko;
    ldsoA[r] = (r * 256 + wid * 64) * 8;
  }
#pragma unroll
  for (int r = 0; r < 4; ++r) {
    int p = r * 256 + tid;
    int row = p >> 2;
    int sko = ((p & 3) ^ ((p >> 3) & 3)) << 3;
    gb[r] = W + (size_t)(n0 + row) * K + sko;
    ldsoB[r] = (r * 256 + wid * 64) * 8;
  }
  int apos[4], bpos[8];
#pragma unroll
  for (int i = 0; i < 4; ++i) {
    int ar = wm * 64 + i * 16 + l16;
    apos[i] = (ar * 4 + (quad ^ ((ar >> 1) & 3))) * 8;
  }
#pragma unroll
  for (int j = 0; j < 8; ++j) {
    int br = wn * 128 + j * 16 + l16;
    bpos[j] = (br * 4 + (quad ^ ((br >> 1) & 3))) * 8;
  }

  const int niter = K >> 5;
#pragma unroll
  for (int t = 0; t < 2; ++t) {
#pragma unroll
    for (int r = 0; r < 2; ++r) gl2lds16(ga[r] + t * 32, &As[t][ldsoA[r]]);
#pragma unroll
    for (int r = 0; r < 4; ++r) gl2lds16(gb[r] + t * 32, &Bs[t][ldsoB[r]]);
  }

  int cur = 0;
  for (int k = 0; k < niter; ++k) {
    if (k == niter - 1) { asm volatile("s_waitcnt vmcnt(0)" ::: "memory"); }
    else               { asm volatile("s_waitcnt vmcnt(6)" ::: "memory"); }
    asm volatile("s_barrier" ::: "memory");

    const bf16* as = As[cur];
    const bf16* bs = Bs[cur];
    bf16x8 af[4], bfr[8];
#pragma unroll
    for (int i = 0; i < 4; ++i) af[i]  = *(const bf16x8*)(as + apos[i]);
#pragma unroll
    for (int j = 0; j < 8; ++j) bfr[j] = *(const bf16x8*)(bs + bpos[j]);
    asm volatile("s_waitcnt lgkmcnt(0)" ::: "memory");

    if (k + 2 < niter) {
      int nb = cur + 2; if (nb >= 3) nb -= 3;
#pragma unroll
      for (int r = 0; r < 2; ++r) gl2lds16(ga[r] + (k + 2) * 32, &As[nb][ldsoA[r]]);
#pragma unroll
      for (int r = 0; r < 4; ++r) gl2lds16(gb[r] + (k + 2) * 32, &Bs[nb][ldsoB[r]]);
    }
#pragma unroll
    for (int i = 0; i < 4; ++i)
#pragma unroll
      for (int j = 0; j < 8; ++j)
        acc[i][j] = __builtin_amdgcn_mfma_f32_16x16x32_bf16(af[i], bfr[j], acc[i][j], 0, 0, 0);
    cur += 1; if (cur == 3) cur = 0;
  }

#pragma unroll
  for (int i = 0; i < 4; ++i) {
    const int gm_base = m0 + wm * 64 + i * 16 + quad * 4;
#pragma unroll
    for (int j = 0; j < 8; ++j) {
      const int gn = n0 + wn * 128 + j * 16 + l16;
      const float bv = bias[gn];
#pragma unroll
      for (int r = 0; r < 4; ++r) {
        const int gm = gm_base + r;
        const size_t off = (size_t)gm * N + gn;
        float v = acc[i][j][r] + bv;
        if (EPI == 0) ((bf16*)Out)[off] = f2b(gelu_fast(v));
        else if (EPI == 2) ((float*)Out)[off] = v * ((const float*)aux0)[off] + ((const float*)aux1)[off];
        else ((float*)Out)[off] = v + ((const float*)aux0)[off];
      }
    }
  }
}

// ---------------- causal depthwise conv ----------------
// Staging fully vectorized: 8 ushort4 (zn) + 4 float4 (wh) wide loads per thread.
// Inner loop: sliding-window register reuse (2 LDS reads + 16 FMA per tap).
__global__ __launch_bounds__(256) void conv_k(
    const bf16* __restrict__ zn,    // [B, L, D] bf16
    const float* __restrict__ wh,   // [L, D] f32
    const float* __restrict__ a,
    float* __restrict__ out)        // [B, L, D] f32
{
  __shared__ float whs[64 * 64];
  __shared__ float znt[128 * 64];   // row r holds u = t0 - sb - 64 + r
  const int tid = threadIdx.x;
  const int dd = tid & 63, ttg = tid >> 6;
  const int t0 = blockIdx.x * 64, d0 = blockIdx.y * 64, b = blockIdx.z;
  const float expa = expf(a[0]);
  const float smax = 20.7f / expa;
  const unsigned short* znu = (const unsigned short*)zn;

  float acc[16];
#pragma unroll
  for (int q = 0; q < 16; ++q) acc[q] = 0.f;

  for (int sb = 0; sb <= t0 + 63; sb += 64) {
    if ((float)sb > smax) break;
    // wh: 1024 float4 chunks; 4 per thread. (sb+row <= t0+63 <= 2047 always)
    float4 wv4[4];
#pragma unroll
    for (int i = 0; i < 4; ++i) {
      int cc = tid + 256 * i;
      int row = cc >> 4, dq = (cc & 15) * 4;
      wv4[i] = *(const float4*)&wh[(size_t)(sb + row) * 1024 + d0 + dq];
    }
    // zn: 2048 ushort4 chunks; 8 per thread.
    ushort4 zv4[8];
#pragma unroll
    for (int i = 0; i < 8; ++i) {
      int cc = tid + 256 * i;
      int row = cc >> 4, dq = (cc & 15) * 4;
      int u = t0 - sb - 64 + row;
      zv4[i] = (u >= 0) ? *(const ushort4*)&znu[((size_t)b * 2048 + u) * 1024 + d0 + dq]
                        : make_ushort4(0, 0, 0, 0);
    }
#pragma unroll
    for (int i = 0; i < 4; ++i) {
      int cc = tid + 256 * i;
      *(float4*)&whs[(cc >> 4) * 64 + (cc & 15) * 4] = wv4[i];
    }
#pragma unroll
    for (int i = 0; i < 8; ++i) {
      int cc = tid + 256 * i;
      float4 o;
      o.x = us2f(zv4[i].x); o.y = us2f(zv4[i].y); o.z = us2f(zv4[i].z); o.w = us2f(zv4[i].w);
      *(float4*)&znt[(cc >> 4) * 64 + (cc & 15) * 4] = o;
    }
    __syncthreads();

    float win[16];
#pragma unroll
    for (int q = 0; q < 16; ++q) win[q] = znt[(ttg * 16 + q + 64) * 64 + dd];
#pragma unroll
    for (int ss = 0; ss < 64; ++ss) {
      float wv = whs[ss * 64 + dd];
#pragma unroll
      for (int q = 0; q < 16; ++q) acc[q] += wv * win[q];
      if (ss < 63) {
#pragma unroll
        for (int q = 15; q >= 1; --q) win[q] = win[q - 1];
        win[0] = znt[(ttg * 16 + 63 - ss) * 64 + dd];
      }
    }
    __syncthreads();
  }
#pragma unroll
  for (int q = 0; q < 16; ++q) {
    int t = t0 + ttg * 16 + q;
    out[((size_t)b * 2048 + t) * 1024 + d0 + dd] = acc[q];
  }
}

extern "C" void kernel_launch(void* const* d_in, const int* in_sizes, int n_in,
                              void* d_out, int out_size, void* d_ws, size_t ws_size,
                              hipStream_t stream)
{
  const float* z      = (const float*)d_in[0];
  const float* x      = (const float*)d_in[1];
  const float* a      = (const float*)d_in[2];
  const float* pe     = (const float*)d_in[3];
  const float* w_pos1 = (const float*)d_in[4];
  const float* b_pos1 = (const float*)d_in[5];
  const float* w_pos2 = (const float*)d_in[6];
  const float* b_pos2 = (const float*)d_in[7];
  const float* w1     = (const float*)d_in[8];
  const float* b1     = (const float*)d_in[9];
  const float* w2     = (const float*)d_in[10];
  const float* b2     = (const float*)d_in[11];
  const float* w3     = (const float*)d_in[12];
  const float* b3     = (const float*)d_in[13];
  const float* w4     = (const float*)d_in[14];
  const float* b4     = (const float*)d_in[15];
  const float* ln_g   = (const float*)d_in[16];
  const float* ln_b   = (const float*)d_in[17];

  char* ws = (char*)d_ws;
  bf16* pe_bf  = (bf16*)(ws + 0);
  bf16* wp1_bf = (bf16*)(ws + 524288);
  bf16* wp2_bf = (bf16*)(ws + 819200);
  bf16* w1_bf  = (bf16*)(ws + 3178496);
  bf16* w2_bf  = (bf16*)(ws + 7372800);
  bf16* w3_bf  = (bf16*)(ws + 11567104);
  bf16* w4_bf  = (bf16*)(ws + 15761408);
  bf16* h1     = (bf16*)(ws + 19955712);
  bf16* zn_bf  = (bf16*)(ws + 24674304);
  bf16* x_bf   = (bf16*)(ws + 41451520);
  float* wh    = (float*)(ws + 58228736);
  float* cwhz  = (float*)(ws + 66617344);
  bf16*  x1n   = (bf16*)(ws + 66617344);
  bf16*  g     = (bf16*)(ws + 100171776);
  float* x1    = (float*)(ws + 24674304);
  float* out   = (float*)d_out;

  CvtSegs segs;
  segs.src[0] = pe;  segs.src[1] = w_pos1; segs.src[2] = w_pos2;
  segs.src[3] = w1;  segs.src[4] = w2;     segs.src[5] = w3; segs.src[6] = w4;
  int bo[8] = {0, 256, 400, 1552, 3600, 5648, 7696, 9744};
  for (int i = 0; i < 8; ++i) segs.blk_off[i] = bo[i];
  cvt7_k<<<9744, 256, 0, stream>>>(segs, (bf16*)ws);
  cvt_k<<<8192, 256, 0, stream>>>(x, x_bf, 8388608);

  // 1. zn = LN(z) -> bf16
  ln_k<<<8192, 256, 0, stream>>>(z, zn_bf, ln_g, ln_b);
  // 2. h1 = gelu(pe @ w_pos1^T + b_pos1) -> bf16   [2048, 1152], K=128
  gemm_k<0><<<dim3(9, 16), 256, 0, stream>>>(pe_bf, wp1_bf, b_pos1, h1, nullptr, nullptr, 2048, 1152, 128);
  // 3. wh = window * (h1 @ w_pos2^T + b_pos2) f32  [2048, 1024], K=1152
  gemm_k<1><<<dim3(8, 16), 256, 0, stream>>>(h1, wp2_bf, b_pos2, wh, a, nullptr, 2048, 1024, 1152);
  // 4. cwhz = causal depthwise conv(zn, wh) f32    [4, 2048, 1024]
  conv_k<<<dim3(32, 16, 4), 256, 0, stream>>>(zn_bf, wh, a, cwhz);
  // 5. g1 = gelu(x @ w1^T + b1) -> bf16            [8192, 2048], K=1024
  gemm256_k<0><<<dim3(8, 64), 256, 0, stream>>>(x_bf, w1_bf, b1, g, nullptr, nullptr, 8192, 2048, 1024);
  // 6. x1 = (g1 @ w2^T + b2) * cwhz + z   f32      [8192, 1024], K=2048
  gemm256_k<2><<<dim3(4, 64), 256, 0, stream>>>(g, w2_bf, b2, x1, cwhz, z, 8192, 1024, 2048);
  // 7. x1n = LN(x1) -> bf16
  ln_k<<<8192, 256, 0, stream>>>(x1, x1n, ln_g, ln_b);
  // 8. g3 = gelu(x1n @ w3^T + b3) -> bf16          [8192, 2048], K=1024
  gemm256_k<0><<<dim3(8, 64), 256, 0, stream>>>(x1n, w3_bf, b3, g, nullptr, nullptr, 8192, 2048, 1024);
  // 9. out = (g3 @ w4^T + b4) + x1  f32            [8192, 1024], K=2048
  gemm256_k<3><<<dim3(4, 64), 256, 0, stream>>>(g, w4_bf, b4, out, x1, nullptr, 8192, 1024, 2048);
}